// Round 4
// baseline (621.887 us; speedup 1.0000x reference)
//
#include <hip/hip_runtime.h>
#include <hip/hip_bf16.h>

#define H 128
#define NT 4
#define CAP 96

typedef __attribute__((ext_vector_type(8))) _Float16 half8;
typedef __attribute__((ext_vector_type(2))) _Float16 half2v;
typedef __attribute__((ext_vector_type(4))) float f32x4;

__device__ __forceinline__ float bf2f(unsigned short u) {
    union { unsigned int i; float f; } v;
    v.i = ((unsigned int)u) << 16;
    return v.f;
}

__device__ __forceinline__ unsigned short f2bf(float f) {
    union { float f; unsigned int i; } v;
    v.f = f;
    unsigned int x = v.i;
    unsigned int r = (x + 0x7fffu + ((x >> 16) & 1u)) >> 16;  // RNE
    return (unsigned short)r;
}

__device__ __forceinline__ float sigmoidf_(float x) {
    return 1.0f / (1.0f + expf(-x));
}

// flag-adaptive fp32 read from raw input buffer (1 = bf16-packed, 0 = fp32)
__device__ __forceinline__ float readf(const void* p, long i, int isbf) {
    return isbf ? bf2f(((const unsigned short*)p)[i]) : ((const float*)p)[i];
}

// ---------------------------------------------------------------------------
// dtype detector: low u16 of each dword as bf16 exponent sanity test.
// ---------------------------------------------------------------------------
__global__ void detect_dtype(const unsigned short* __restrict__ states_u16,
                             int* __restrict__ flag) {
    __shared__ int cnt;
    if (threadIdx.x == 0) cnt = 0;
    __syncthreads();
    int local = 0;
    for (int i = threadIdx.x; i < 1024; i += 256) {
        unsigned short u = states_u16[2 * i];
        int e = (u >> 7) & 0xFF;
        if (e >= 96 && e <= 158) local++;
    }
    atomicAdd(&cnt, local);
    __syncthreads();
    if (threadIdx.x == 0) *flag = (cnt >= 512) ? 1 : 0;
}

__global__ void cast_h16(const void* __restrict__ in, _Float16* __restrict__ out,
                         const int* __restrict__ flag, int n) {
    int i = blockIdx.x * blockDim.x + threadIdx.x;
    if (i < n) out[i] = (_Float16)readf(in, i, *flag);
}

// type_W [L*NT][k:128][c:128] -> WT16 [L*NT][c:128][k:128] fp16
__global__ void prep_WT(const void* __restrict__ W, _Float16* __restrict__ WT,
                        const int* __restrict__ flag, int total) {
    int i = blockIdx.x * blockDim.x + threadIdx.x;
    if (i >= total) return;
    int mat = i >> 14;
    int rem = i & 16383;
    int c = rem >> 7, k = rem & 127;
    WT[i] = (_Float16)readf(W, ((long)mat << 14) + k * H + c, *flag);
}

// gru kernel [L][k:128][c:384] -> gT [L][c:384][k:128] fp16
__global__ void prep_gT(const void* __restrict__ g, _Float16* __restrict__ gT,
                        const int* __restrict__ flag, int total) {
    int i = blockIdx.x * blockDim.x + threadIdx.x;
    if (i >= total) return;
    int L = i / 49152, rem = i % 49152;
    int c = rem >> 7, k = rem & 127;
    gT[i] = (_Float16)readf(g, (long)L * 49152 + k * 384 + c, *flag);
}

// biases -> fp32 ws; gbsum[L][384] = gb[L][0][c] + gb[L][1][c]
__global__ void prep_bias(const void* __restrict__ type_b, const void* __restrict__ grub,
                          float* __restrict__ bf_, float* __restrict__ gbf,
                          float* __restrict__ gbsum, const int* __restrict__ flag) {
    int i = blockIdx.x * blockDim.x + threadIdx.x;
    int fl = *flag;
    if (i < 1024) bf_[i] = readf(type_b, i, fl);
    if (i < 1536) gbf[i] = readf(grub, i, fl);
    if (i < 768) {
        int L = i / 384, c = i % 384;
        gbsum[i] = readf(grub, (long)L * 768 + c, fl) +
                   readf(grub, (long)L * 768 + 384 + c, fl);
    }
}

// ---------------------------------------------------------------------------
// bucket edges by dst (counts pre-zeroed by memset)
// ---------------------------------------------------------------------------
__global__ void place_edges(const int* __restrict__ edges, int* __restrict__ counts,
                            int* __restrict__ buckets, int NE) {
    int e = blockIdx.x * 256 + threadIdx.x;
    if (e >= NE) return;
    int t = edges[3 * e], src = edges[3 * e + 1], dst = edges[3 * e + 2];
    int slot = atomicAdd(&counts[dst], 1);
    if (slot < CAP) buckets[(size_t)dst * CAP + slot] = src | (t << 17);
}

// ---------------------------------------------------------------------------
// msg GEMM (MFMA, no LDS): M[t][n][c] = sum_k h16[n][k]*W[t][k][c] + b[t][c]
// grid ((NN+63)/64, NT), block 256 = 4 waves; wave w: rows w*16..+16 x 128c
// ---------------------------------------------------------------------------
__global__ __launch_bounds__(256) void msg_mfma(
    const _Float16* __restrict__ h16,   // [NN][128]
    const _Float16* __restrict__ WTL,   // [NT][128c][128k] this layer
    const float* __restrict__ bL,       // [NT][128]
    _Float16* __restrict__ M,           // [NT][NN][128]
    int NN) {
    const int t = blockIdx.y;
    const int n0 = blockIdx.x * 64;
    const int tid = threadIdx.x;
    const int wave = tid >> 6, lane = tid & 63;
    const int m = lane & 15, quad = lane >> 4;
    int arow = n0 + wave * 16 + m;
    if (arow >= NN) arow = NN - 1;   // clamped rows produce garbage C-rows that
                                     // are discarded by the epilogue guard

    half8 aF[4];
#pragma unroll
    for (int kk = 0; kk < 4; kk++)
        aF[kk] = *(const half8*)&h16[(size_t)arow * H + kk * 32 + quad * 8];

    const _Float16* Wt = WTL + (size_t)t * H * H;
    f32x4 acc[8] = {};
#pragma unroll
    for (int kk = 0; kk < 4; kk++) {
#pragma unroll
        for (int ct = 0; ct < 8; ct++) {
            half8 b = *(const half8*)&Wt[(size_t)(ct * 16 + m) * H + kk * 32 + quad * 8];
            acc[ct] = __builtin_amdgcn_mfma_f32_16x16x32_f16(aF[kk], b, acc[ct], 0, 0, 0);
        }
    }

#pragma unroll
    for (int ct = 0; ct < 8; ct++) {
        int col = ct * 16 + m;
        float bias = bL[t * H + col];
#pragma unroll
        for (int i = 0; i < 4; i++) {
            int nn = n0 + wave * 16 + quad * 4 + i;
            if (nn < NN)
                M[((size_t)t * NN + nn) * H + col] = (_Float16)(acc[ct][i] + bias);
        }
    }
}

// ---------------------------------------------------------------------------
// gather: agg16[n] = sum over in-edges of M[t][src]  (one wave per node,
// 4-wide unrolled bucket walk for MLP)
// ---------------------------------------------------------------------------
__global__ __launch_bounds__(256) void gather_agg(
    const _Float16* __restrict__ M, const int* __restrict__ counts,
    const int* __restrict__ buckets, _Float16* __restrict__ agg16, int NN) {
    int node = blockIdx.x * 4 + (threadIdx.x >> 6);
    int lane = threadIdx.x & 63;
    if (node >= NN) return;
    int cnt = counts[node];
    if (cnt > CAP) cnt = CAP;
    float a0 = 0.0f, a1 = 0.0f;
    const int* bkt = buckets + (size_t)node * CAP;
    int e = 0;
    for (; e + 4 <= cnt; e += 4) {
        int4 p4 = *(const int4*)&bkt[e];
        half2v v0 = *(const half2v*)&M[(((size_t)(p4.x >> 17) * NN) + (p4.x & 131071)) * H + lane * 2];
        half2v v1 = *(const half2v*)&M[(((size_t)(p4.y >> 17) * NN) + (p4.y & 131071)) * H + lane * 2];
        half2v v2 = *(const half2v*)&M[(((size_t)(p4.z >> 17) * NN) + (p4.z & 131071)) * H + lane * 2];
        half2v v3 = *(const half2v*)&M[(((size_t)(p4.w >> 17) * NN) + (p4.w & 131071)) * H + lane * 2];
        a0 += (float)v0[0] + (float)v1[0] + (float)v2[0] + (float)v3[0];
        a1 += (float)v0[1] + (float)v1[1] + (float)v2[1] + (float)v3[1];
    }
    for (; e < cnt; e++) {
        int p = bkt[e];
        half2v v = *(const half2v*)&M[(((size_t)(p >> 17) * NN) + (p & 131071)) * H + lane * 2];
        a0 += (float)v[0];
        a1 += (float)v[1];
    }
    half2v o;
    o[0] = (_Float16)a0;
    o[1] = (_Float16)a1;
    *(half2v*)&agg16[(size_t)node * H + lane * 2] = o;
}

// ---------------------------------------------------------------------------
// fused GRU (MFMA, no LDS). grid (NN+63)/64, block 256.
// Phase order r -> c -> z keeps register pressure ~150.
// ---------------------------------------------------------------------------
__global__ __launch_bounds__(256) void gru_mfma(
    const _Float16* __restrict__ agg16,  // [NN][128]
    const _Float16* __restrict__ h16,    // [NN][128]
    const _Float16* __restrict__ gkT,    // [384c][128k] this layer
    const _Float16* __restrict__ grT,    // [384c][128k] this layer
    const float* __restrict__ gbsumL,    // [384]
    const float* __restrict__ gbL,       // [2][384]
    _Float16* __restrict__ h16next,      // [NN][128]
    void* __restrict__ outbuf,           // final output or nullptr
    const int* __restrict__ flag, int NN) {
    const int n0 = blockIdx.x * 64;
    const int tid = threadIdx.x;
    const int wave = tid >> 6, lane = tid & 63;
    const int m = lane & 15, quad = lane >> 4;
    int arow = n0 + wave * 16 + m;
    if (arow >= NN) arow = NN - 1;

    half8 aA[4], aH[4];
#pragma unroll
    for (int kk = 0; kk < 4; kk++) {
        aA[kk] = *(const half8*)&agg16[(size_t)arow * H + kk * 32 + quad * 8];
        aH[kk] = *(const half8*)&h16[(size_t)arow * H + kk * 32 + quad * 8];
    }

    // ---- r gate (cols 128..255) ----
    float rv[8][4];
    {
        f32x4 acc[8] = {};
#pragma unroll
        for (int kk = 0; kk < 4; kk++) {
#pragma unroll
            for (int ct = 0; ct < 8; ct++) {
                half8 b = *(const half8*)&gkT[(size_t)(H + ct * 16 + m) * H + kk * 32 + quad * 8];
                acc[ct] = __builtin_amdgcn_mfma_f32_16x16x32_f16(aA[kk], b, acc[ct], 0, 0, 0);
            }
        }
#pragma unroll
        for (int kk = 0; kk < 4; kk++) {
#pragma unroll
            for (int ct = 0; ct < 8; ct++) {
                half8 b = *(const half8*)&grT[(size_t)(H + ct * 16 + m) * H + kk * 32 + quad * 8];
                acc[ct] = __builtin_amdgcn_mfma_f32_16x16x32_f16(aH[kk], b, acc[ct], 0, 0, 0);
            }
        }
#pragma unroll
        for (int ct = 0; ct < 8; ct++) {
            float bias = gbsumL[H + ct * 16 + m];
#pragma unroll
            for (int i = 0; i < 4; i++) rv[ct][i] = sigmoidf_(acc[ct][i] + bias);
        }
    }

    // ---- candidate c (cols 256..383) ----
    float cc[8][4];
    {
        f32x4 xh[8] = {}, hh[8] = {};
#pragma unroll
        for (int kk = 0; kk < 4; kk++) {
#pragma unroll
            for (int ct = 0; ct < 8; ct++) {
                half8 bx = *(const half8*)&gkT[(size_t)(2 * H + ct * 16 + m) * H + kk * 32 + quad * 8];
                half8 bh = *(const half8*)&grT[(size_t)(2 * H + ct * 16 + m) * H + kk * 32 + quad * 8];
                xh[ct] = __builtin_amdgcn_mfma_f32_16x16x32_f16(aA[kk], bx, xh[ct], 0, 0, 0);
                hh[ct] = __builtin_amdgcn_mfma_f32_16x16x32_f16(aH[kk], bh, hh[ct], 0, 0, 0);
            }
        }
#pragma unroll
        for (int ct = 0; ct < 8; ct++) {
            int col = 2 * H + ct * 16 + m;
            float b0 = gbL[col];
            float b1 = gbL[384 + col];
#pragma unroll
            for (int i = 0; i < 4; i++)
                cc[ct][i] = tanhf((xh[ct][i] + b0) + rv[ct][i] * (hh[ct][i] + b1));
        }
    }

    // ---- z gate (cols 0..127) + blend + write ----
    {
        f32x4 acc[8] = {};
#pragma unroll
        for (int kk = 0; kk < 4; kk++) {
#pragma unroll
            for (int ct = 0; ct < 8; ct++) {
                half8 b = *(const half8*)&gkT[(size_t)(ct * 16 + m) * H + kk * 32 + quad * 8];
                acc[ct] = __builtin_amdgcn_mfma_f32_16x16x32_f16(aA[kk], b, acc[ct], 0, 0, 0);
            }
        }
#pragma unroll
        for (int kk = 0; kk < 4; kk++) {
#pragma unroll
            for (int ct = 0; ct < 8; ct++) {
                half8 b = *(const half8*)&grT[(size_t)(ct * 16 + m) * H + kk * 32 + quad * 8];
                acc[ct] = __builtin_amdgcn_mfma_f32_16x16x32_f16(aH[kk], b, acc[ct], 0, 0, 0);
            }
        }
        const int fl = outbuf ? *flag : 0;
#pragma unroll
        for (int ct = 0; ct < 8; ct++) {
            int col = ct * 16 + m;
            float bias = gbsumL[col];
#pragma unroll
            for (int i = 0; i < 4; i++) {
                int nn = n0 + wave * 16 + quad * 4 + i;
                if (nn < NN) {
                    float z = sigmoidf_(acc[ct][i] + bias);
                    float hv = (float)h16[(size_t)nn * H + col];
                    float hn = z * hv + (1.0f - z) * cc[ct][i];
                    size_t oi = (size_t)nn * H + col;
                    h16next[oi] = (_Float16)hn;
                    if (outbuf) {
                        if (fl) ((unsigned short*)outbuf)[oi] = f2bf(hn);
                        else    ((float*)outbuf)[oi] = hn;
                    }
                }
            }
        }
    }
}

// ---------------------------------------------------------------------------
extern "C" void kernel_launch(void* const* d_in, const int* in_sizes, int n_in,
                              void* d_out, int out_size, void* d_ws, size_t ws_size,
                              hipStream_t stream) {
    const void* states = d_in[0];
    const int*  edges  = (const int*)d_in[1];
    const void* type_W = d_in[2];
    const void* type_b = d_in[3];
    const void* gruk   = d_in[4];
    const void* grur   = d_in[5];
    const void* grub   = d_in[6];

    const int NN = in_sizes[0] / H;    // 50000
    const int NE = in_sizes[1] / 3;    // 400000
    const int nW = in_sizes[2];        // L*NT*128*128
    const int LAYERS = nW / (NT * H * H);

    // --- workspace layout ---
    char* w = (char*)d_ws;
    int* flag = (int*)w;                              w += 64;
    _Float16* h16A  = (_Float16*)w;                   w += (size_t)NN * H * 2;
    _Float16* h16B  = (_Float16*)w;                   w += (size_t)NN * H * 2;
    _Float16* agg16 = (_Float16*)w;                   w += (size_t)NN * H * 2;
    _Float16* M     = (_Float16*)w;                   w += (size_t)NT * NN * H * 2;
    _Float16* WT16  = (_Float16*)w;                   w += (size_t)nW * 2;
    _Float16* gkT16 = (_Float16*)w;                   w += (size_t)LAYERS * 384 * H * 2;
    _Float16* grT16 = (_Float16*)w;                   w += (size_t)LAYERS * 384 * H * 2;
    float* bf_   = (float*)w;                         w += (size_t)LAYERS * NT * H * 4;
    float* gbf   = (float*)w;                         w += (size_t)LAYERS * 2 * 384 * 4;
    float* gbsum = (float*)w;                         w += (size_t)LAYERS * 384 * 4;
    int* counts  = (int*)w;                           w += (size_t)NN * 4;
    int* buckets = (int*)w;                           // [NN][CAP]

    detect_dtype<<<1, 256, 0, stream>>>((const unsigned short*)states, flag);

    cast_h16<<<(NN * H + 255) / 256, 256, 0, stream>>>(states, h16A, flag, NN * H);
    prep_WT<<<(nW + 255) / 256, 256, 0, stream>>>(type_W, WT16, flag, nW);
    const int ng = LAYERS * 384 * H;
    prep_gT<<<(ng + 255) / 256, 256, 0, stream>>>(gruk, gkT16, flag, ng);
    prep_gT<<<(ng + 255) / 256, 256, 0, stream>>>(grur, grT16, flag, ng);
    prep_bias<<<6, 256, 0, stream>>>(type_b, grub, bf_, gbf, gbsum, flag);

    hipMemsetAsync(counts, 0, (size_t)NN * 4, stream);
    place_edges<<<(NE + 255) / 256, 256, 0, stream>>>(edges, counts, buckets, NE);

    const int ntile = (NN + 63) / 64;
    for (int L = 0; L < LAYERS; L++) {
        const _Float16* hcur = (L & 1) ? h16B : h16A;
        _Float16* hnext      = (L & 1) ? h16A : h16B;

        dim3 g1(ntile, NT);
        msg_mfma<<<g1, 256, 0, stream>>>(
            hcur, WT16 + (size_t)L * NT * H * H, bf_ + (size_t)L * NT * H, M, NN);

        gather_agg<<<(NN + 3) / 4, 256, 0, stream>>>(M, counts, buckets, agg16, NN);

        gru_mfma<<<ntile, 256, 0, stream>>>(
            agg16, hcur,
            gkT16 + (size_t)L * 384 * H,
            grT16 + (size_t)L * 384 * H,
            gbsum + (size_t)L * 384,
            gbf + (size_t)L * 2 * 384,
            hnext,
            (L == LAYERS - 1) ? d_out : nullptr,
            flag, NN);
    }
}

// Round 5
// 408.675 us; speedup vs baseline: 1.5217x; 1.5217x over previous
//
#include <hip/hip_runtime.h>
#include <hip/hip_bf16.h>

#define H 128
#define NT 4
#define CAP 96
#define BK 64
#define LDK 72   // BK + 8 pad (halfs) -> 144 B stride, conflict-free

typedef __attribute__((ext_vector_type(8))) _Float16 half8;
typedef __attribute__((ext_vector_type(2))) _Float16 half2v;
typedef __attribute__((ext_vector_type(4))) float f32x4;

__device__ __forceinline__ float bf2f(unsigned short u) {
    union { unsigned int i; float f; } v;
    v.i = ((unsigned int)u) << 16;
    return v.f;
}

__device__ __forceinline__ unsigned short f2bf(float f) {
    union { float f; unsigned int i; } v;
    v.f = f;
    unsigned int x = v.i;
    unsigned int r = (x + 0x7fffu + ((x >> 16) & 1u)) >> 16;  // RNE
    return (unsigned short)r;
}

// flag-adaptive fp32 read from raw input buffer (1 = bf16-packed, 0 = fp32)
__device__ __forceinline__ float readf(const void* p, long i, int isbf) {
    return isbf ? bf2f(((const unsigned short*)p)[i]) : ((const float*)p)[i];
}

// ---------------------------------------------------------------------------
// dtype detector: low u16 of each dword as bf16 exponent sanity test.
// ---------------------------------------------------------------------------
__global__ void detect_dtype(const unsigned short* __restrict__ states_u16,
                             int* __restrict__ flag) {
    __shared__ int cnt;
    if (threadIdx.x == 0) cnt = 0;
    __syncthreads();
    int local = 0;
    for (int i = threadIdx.x; i < 1024; i += 256) {
        unsigned short u = states_u16[2 * i];
        int e = (u >> 7) & 0xFF;
        if (e >= 96 && e <= 158) local++;
    }
    atomicAdd(&cnt, local);
    __syncthreads();
    if (threadIdx.x == 0) *flag = (cnt >= 512) ? 1 : 0;
}

__global__ void cast_h16(const void* __restrict__ in, _Float16* __restrict__ out,
                         const int* __restrict__ flag, int n) {
    int i = blockIdx.x * blockDim.x + threadIdx.x;
    if (i < n) out[i] = (_Float16)readf(in, i, *flag);
}

// type_W [L][t][k][c] -> BTw [L][c:128][t*128+k : 512]
__global__ void prep_BTw(const void* __restrict__ W, _Float16* __restrict__ BTw,
                         const int* __restrict__ flag, int total) {
    int i = blockIdx.x * 256 + threadIdx.x;
    if (i >= total) return;
    int l = i >> 16;            // 128*512 per layer
    int rem = i & 65535;
    int c = rem >> 9, kk = rem & 511;
    int t = kk >> 7, k = kk & 127;
    BTw[i] = (_Float16)readf(W, (((long)(l * NT + t) * H) + k) * H + c, *flag);
}

// gru kernels -> BTg [L][col:512][k:256]
//  col<256 (z,r summed): k<128 -> gk[k][col], k>=128 -> gr[k-128][col]
//  col 256..383 (xh):    k<128 -> gk[k][col], else 0
//  col 384..511 (hh):    k>=128 -> gr[k-128][col-128], else 0
__global__ void prep_BTg(const void* __restrict__ gk, const void* __restrict__ gr,
                         _Float16* __restrict__ BTg, const int* __restrict__ flag,
                         int total) {
    int i = blockIdx.x * 256 + threadIdx.x;
    if (i >= total) return;
    int l = i >> 17;            // 512*256 per layer
    int rem = i & 131071;
    int col = rem >> 8, k = rem & 255;
    int fl = *flag;
    float v = 0.0f;
    if (col < 384) {
        if (k < 128) v = readf(gk, ((long)l * H + k) * 384 + col, fl);
        else if (col < 256) v = readf(gr, ((long)l * H + (k - 128)) * 384 + col, fl);
    } else {
        if (k >= 128) v = readf(gr, ((long)l * H + (k - 128)) * 384 + (col - 128), fl);
    }
    BTg[i] = (_Float16)v;
}

// btab[L][t][128] = type_b; gbsum[L][256] = gb0+gb1 (z,r); gb0c/gb1c[L][128] (c-gate)
__global__ void prep_bias2(const void* __restrict__ type_b, const void* __restrict__ grub,
                           float* __restrict__ btab, float* __restrict__ gbsum,
                           float* __restrict__ gb0c, float* __restrict__ gb1c,
                           const int* __restrict__ flag, int LAYERS) {
    int i = blockIdx.x * 256 + threadIdx.x;
    int fl = *flag;
    if (i < LAYERS * NT * H) btab[i] = readf(type_b, i, fl);
    if (i < LAYERS * 256) {
        int l = i >> 8, c = i & 255;
        gbsum[i] = readf(grub, (long)l * 768 + c, fl) +
                   readf(grub, (long)l * 768 + 384 + c, fl);
    }
    if (i < LAYERS * H) {
        int l = i >> 7, c = i & 127;
        gb0c[i] = readf(grub, (long)l * 768 + 256 + c, fl);
        gb1c[i] = readf(grub, (long)l * 768 + 384 + 256 + c, fl);
    }
}

// ---------------------------------------------------------------------------
// bucket edges by dst (counts pre-zeroed by memset)
// ---------------------------------------------------------------------------
__global__ void place_edges(const int* __restrict__ edges, int* __restrict__ counts,
                            int* __restrict__ buckets, int NE) {
    int e = blockIdx.x * 256 + threadIdx.x;
    if (e >= NE) return;
    int t = edges[3 * e], src = edges[3 * e + 1], dst = edges[3 * e + 2];
    int slot = atomicAdd(&counts[dst], 1);
    if (slot < CAP) buckets[(size_t)dst * CAP + slot] = src | (t << 17);
}

// ---------------------------------------------------------------------------
// gather4: A4[node][t][:] = sum of h16[src] over in-edges of type t (fp32 acc)
// one wave per node; also records per-type counts (cnt4).
// ---------------------------------------------------------------------------
__global__ __launch_bounds__(256) void gather4(
    const _Float16* __restrict__ h16, const int* __restrict__ counts,
    const int* __restrict__ buckets, _Float16* __restrict__ A4,
    int4* __restrict__ cnt4, int NN) {
    int node = blockIdx.x * 4 + (threadIdx.x >> 6);
    int lane = threadIdx.x & 63;
    if (node >= NN) return;
    int cnt = counts[node];
    if (cnt > CAP) cnt = CAP;
    const int* bkt = buckets + (size_t)node * CAP;

    float a0x = 0, a0y = 0, a1x = 0, a1y = 0;
    float a2x = 0, a2y = 0, a3x = 0, a3y = 0;
    int c0 = 0, c1 = 0, c2 = 0, c3 = 0;

#define ACC_EDGE(P, V) { int t_ = (P) >> 17;                                   \
        float vx_ = (float)(V)[0], vy_ = (float)(V)[1];                        \
        if (t_ == 0)      { a0x += vx_; a0y += vy_; c0++; }                    \
        else if (t_ == 1) { a1x += vx_; a1y += vy_; c1++; }                    \
        else if (t_ == 2) { a2x += vx_; a2y += vy_; c2++; }                    \
        else              { a3x += vx_; a3y += vy_; c3++; } }

    int e = 0;
    for (; e + 4 <= cnt; e += 4) {
        int4 p4 = *(const int4*)&bkt[e];
        half2v v0 = *(const half2v*)&h16[(size_t)(p4.x & 0x1FFFF) * H + lane * 2];
        half2v v1 = *(const half2v*)&h16[(size_t)(p4.y & 0x1FFFF) * H + lane * 2];
        half2v v2 = *(const half2v*)&h16[(size_t)(p4.z & 0x1FFFF) * H + lane * 2];
        half2v v3 = *(const half2v*)&h16[(size_t)(p4.w & 0x1FFFF) * H + lane * 2];
        ACC_EDGE(p4.x, v0); ACC_EDGE(p4.y, v1);
        ACC_EDGE(p4.z, v2); ACC_EDGE(p4.w, v3);
    }
    for (; e < cnt; e++) {
        int p = bkt[e];
        half2v v = *(const half2v*)&h16[(size_t)(p & 0x1FFFF) * H + lane * 2];
        ACC_EDGE(p, v);
    }
#undef ACC_EDGE

    half2v o;
    size_t base = (size_t)node * 4 * H + lane * 2;
    o[0] = (_Float16)a0x; o[1] = (_Float16)a0y; *(half2v*)&A4[base] = o;
    o[0] = (_Float16)a1x; o[1] = (_Float16)a1y; *(half2v*)&A4[base + H] = o;
    o[0] = (_Float16)a2x; o[1] = (_Float16)a2y; *(half2v*)&A4[base + 2 * H] = o;
    o[0] = (_Float16)a3x; o[1] = (_Float16)a3y; *(half2v*)&A4[base + 3 * H] = o;
    if (lane == 0) cnt4[node] = make_int4(c0, c1, c2, c3);
}

// ---------------------------------------------------------------------------
// Tiled MFMA GEMM: C[row][col0+cl] = sum_k A(row,k) * BT[col][k]  (+ cnt bias)
// A(row,k) = k<ksplit ? A0[row*astr0+k] : A1[row*astr1+(k-ksplit)]
// Block 128x128, BK=64, 4 waves each 64x64. Per-coltile K-range via packed
// bytes (chunk units of 64): kc0=(kstartB>>(8y))&255, kc1=(kendB>>(8y))&255.
// ---------------------------------------------------------------------------
__global__ __launch_bounds__(256) void gemm_tiled(
    const _Float16* __restrict__ A0, int astr0,
    const _Float16* __restrict__ A1, int astr1, int ksplit,
    const _Float16* __restrict__ BT, int bstr,
    _Float16* __restrict__ C, int cstr,
    const int4* __restrict__ cnt4, const float* __restrict__ btab,
    int kstartB, int kendB, int Mrows) {
    __shared__ _Float16 As[128 * LDK];
    __shared__ _Float16 Bs[128 * LDK];

    const int row0 = blockIdx.x * 128;
    const int y = blockIdx.y;
    const int col0 = y * 128;
    const int tid = threadIdx.x;
    const int wave = tid >> 6, lane = tid & 63;
    const int m = lane & 15, quad = lane >> 4;
    const int wr = (wave & 1) * 64, wc = (wave >> 1) * 64;

    const int kc0 = (kstartB >> (y * 8)) & 0xFF;
    const int kc1 = (kendB >> (y * 8)) & 0xFF;

    f32x4 acc[4][4] = {};

    for (int kc = kc0; kc < kc1; kc++) {
        const int k0 = kc * BK;
        const _Float16* Ap;
        int astr, kof;
        if (k0 < ksplit) { Ap = A0; astr = astr0; kof = k0; }
        else             { Ap = A1; astr = astr1; kof = k0 - ksplit; }

        __syncthreads();
#pragma unroll
        for (int p = 0; p < 4; p++) {          // A tile 128 x 64
            int idx = p * 256 + tid;
            int r = idx >> 3, k8 = (idx & 7) * 8;
            int rg = row0 + r;
            if (rg >= Mrows) rg = Mrows - 1;
            *(half8*)&As[r * LDK + k8] = *(const half8*)&Ap[(size_t)rg * astr + kof + k8];
        }
#pragma unroll
        for (int p = 0; p < 4; p++) {          // B tile 128 x 64
            int idx = p * 256 + tid;
            int c = idx >> 3, k8 = (idx & 7) * 8;
            *(half8*)&Bs[c * LDK + k8] = *(const half8*)&BT[(size_t)(col0 + c) * bstr + k0 + k8];
        }
        __syncthreads();

#pragma unroll
        for (int ks = 0; ks < 2; ks++) {
            half8 a[4], b[4];
#pragma unroll
            for (int mt = 0; mt < 4; mt++)
                a[mt] = *(const half8*)&As[(wr + mt * 16 + m) * LDK + ks * 32 + quad * 8];
#pragma unroll
            for (int nt = 0; nt < 4; nt++)
                b[nt] = *(const half8*)&Bs[(wc + nt * 16 + m) * LDK + ks * 32 + quad * 8];
#pragma unroll
            for (int mt = 0; mt < 4; mt++)
#pragma unroll
                for (int nt = 0; nt < 4; nt++)
                    acc[mt][nt] = __builtin_amdgcn_mfma_f32_16x16x32_f16(
                        a[mt], b[nt], acc[mt][nt], 0, 0, 0);
        }
    }

#pragma unroll
    for (int mt = 0; mt < 4; mt++) {
#pragma unroll
        for (int i = 0; i < 4; i++) {
            int row = row0 + wr + mt * 16 + quad * 4 + i;
            if (row >= Mrows) continue;
            if (cnt4) {
                int4 c4 = cnt4[row];
#pragma unroll
                for (int nt = 0; nt < 4; nt++) {
                    int cl = wc + nt * 16 + m;
                    float bias = c4.x * btab[cl] + c4.y * btab[128 + cl] +
                                 c4.z * btab[256 + cl] + c4.w * btab[384 + cl];
                    C[(size_t)row * cstr + col0 + cl] = (_Float16)(acc[mt][nt][i] + bias);
                }
            } else {
#pragma unroll
                for (int nt = 0; nt < 4; nt++) {
                    int cl = wc + nt * 16 + m;
                    C[(size_t)row * cstr + col0 + cl] = (_Float16)acc[mt][nt][i];
                }
            }
        }
    }
}

// ---------------------------------------------------------------------------
// gate: elementwise GRU from preact [NN][512] = [S_zr(256) | xh(128) | hh(128)]
// ---------------------------------------------------------------------------
__global__ __launch_bounds__(256) void gate_kernel(
    const _Float16* __restrict__ pre, const _Float16* __restrict__ h16,
    const float* __restrict__ gbsum,  // [256]
    const float* __restrict__ gb0c,   // [128]
    const float* __restrict__ gb1c,   // [128]
    _Float16* __restrict__ hnext, void* __restrict__ outbuf,
    const int* __restrict__ flag, int NN) {
    int gid = blockIdx.x * 256 + threadIdx.x;
    int row = gid >> 4, cg = (gid & 15) * 8;
    if (row >= NN) return;
    const _Float16* pr = pre + (size_t)row * 512;
    half8 Sz = *(const half8*)&pr[cg];
    half8 Sr = *(const half8*)&pr[128 + cg];
    half8 xh = *(const half8*)&pr[256 + cg];
    half8 hh = *(const half8*)&pr[384 + cg];
    half8 hv = *(const half8*)&h16[(size_t)row * H + cg];
    half8 ho;
    float of[8];
#pragma unroll
    for (int j = 0; j < 8; j++) {
        float z = 1.0f / (1.0f + __expf(-((float)Sz[j] + gbsum[cg + j])));
        float r = 1.0f / (1.0f + __expf(-((float)Sr[j] + gbsum[128 + cg + j])));
        float cc = tanhf(((float)xh[j] + gb0c[cg + j]) + r * ((float)hh[j] + gb1c[cg + j]));
        float hn = z * (float)hv[j] + (1.0f - z) * cc;
        ho[j] = (_Float16)hn;
        of[j] = hn;
    }
    *(half8*)&hnext[(size_t)row * H + cg] = ho;
    if (outbuf) {
        size_t o = (size_t)row * H + cg;
        if (*flag) {
            unsigned short* op = (unsigned short*)outbuf + o;
            *(ushort4*)op = make_ushort4(f2bf(of[0]), f2bf(of[1]), f2bf(of[2]), f2bf(of[3]));
            *(ushort4*)(op + 4) = make_ushort4(f2bf(of[4]), f2bf(of[5]), f2bf(of[6]), f2bf(of[7]));
        } else {
            float* op = (float*)outbuf + o;
            *(float4*)op = make_float4(of[0], of[1], of[2], of[3]);
            *(float4*)(op + 4) = make_float4(of[4], of[5], of[6], of[7]);
        }
    }
}

// ---------------------------------------------------------------------------
extern "C" void kernel_launch(void* const* d_in, const int* in_sizes, int n_in,
                              void* d_out, int out_size, void* d_ws, size_t ws_size,
                              hipStream_t stream) {
    const void* states = d_in[0];
    const int*  edges  = (const int*)d_in[1];
    const void* type_W = d_in[2];
    const void* type_b = d_in[3];
    const void* gruk   = d_in[4];
    const void* grur   = d_in[5];
    const void* grub   = d_in[6];

    const int NN = in_sizes[0] / H;    // 50000
    const int NE = in_sizes[1] / 3;    // 400000
    const int nW = in_sizes[2];        // L*NT*128*128
    const int LAYERS = nW / (NT * H * H);

    // --- workspace layout ---
    char* w = (char*)d_ws;
    int* flag = (int*)w;                               w += 64;
    _Float16* h16A  = (_Float16*)w;                    w += (size_t)NN * H * 2;
    _Float16* h16B  = (_Float16*)w;                    w += (size_t)NN * H * 2;
    _Float16* agg16 = (_Float16*)w;                    w += (size_t)NN * H * 2;
    _Float16* A4    = (_Float16*)w;                    w += (size_t)NN * 4 * H * 2;
    _Float16* preact = A4;  // aliased: A4 dead before preact written (same size)
    _Float16* BTw = (_Float16*)w;                      w += (size_t)LAYERS * H * 512 * 2;
    _Float16* BTg = (_Float16*)w;                      w += (size_t)LAYERS * 512 * 256 * 2;
    float* btab  = (float*)w;                          w += (size_t)LAYERS * NT * H * 4;
    float* gbsum = (float*)w;                          w += (size_t)LAYERS * 256 * 4;
    float* gb0c  = (float*)w;                          w += (size_t)LAYERS * H * 4;
    float* gb1c  = (float*)w;                          w += (size_t)LAYERS * H * 4;
    int* counts  = (int*)w;                            w += (size_t)NN * 4;
    int4* cnt4   = (int4*)w;                           w += (size_t)NN * 16;
    int* buckets = (int*)w;                            // [NN][CAP]

    detect_dtype<<<1, 256, 0, stream>>>((const unsigned short*)states, flag);

    cast_h16<<<(NN * H + 255) / 256, 256, 0, stream>>>(states, h16A, flag, NN * H);
    prep_BTw<<<(LAYERS * 65536 + 255) / 256, 256, 0, stream>>>(type_W, BTw, flag,
                                                               LAYERS * 65536);
    prep_BTg<<<(LAYERS * 131072 + 255) / 256, 256, 0, stream>>>(gruk, grur, BTg, flag,
                                                                LAYERS * 131072);
    prep_bias2<<<4, 256, 0, stream>>>(type_b, grub, btab, gbsum, gb0c, gb1c, flag, LAYERS);

    hipMemsetAsync(counts, 0, (size_t)NN * 4, stream);
    place_edges<<<(NE + 255) / 256, 256, 0, stream>>>(edges, counts, buckets, NE);

    const int rtiles = (NN + 127) / 128;
    for (int L = 0; L < LAYERS; L++) {
        const _Float16* hcur = (L & 1) ? h16B : h16A;
        _Float16* hnext      = (L & 1) ? h16A : h16B;

        gather4<<<(NN + 3) / 4, 256, 0, stream>>>(hcur, counts, buckets, A4, cnt4, NN);

        // agg = A4 @ Wstack + cnt-bias : M=NN, N=128, K=512 (8 chunks)
        gemm_tiled<<<dim3(rtiles, 1), 256, 0, stream>>>(
            A4, 512, A4, 512, 1 << 30,
            BTw + (size_t)L * H * 512, 512,
            agg16, H,
            cnt4, btab + (size_t)L * NT * H,
            0x00, 0x08, NN);

        // preact = [agg|h] @ BTg : M=NN, N=512, per-tile K-ranges
        gemm_tiled<<<dim3(rtiles, 4), 256, 0, stream>>>(
            agg16, H, hcur, H, 128,
            BTg + (size_t)L * 512 * 256, 256,
            preact, 512,
            nullptr, nullptr,
            0x02000000, 0x04020404, NN);

        gate_kernel<<<(NN * 16 + 255) / 256, 256, 0, stream>>>(
            preact, hcur,
            gbsum + (size_t)L * 256, gb0c + (size_t)L * H, gb1c + (size_t)L * H,
            hnext, (L == LAYERS - 1) ? d_out : nullptr, flag, NN);
    }
}

// Round 6
// 326.352 us; speedup vs baseline: 1.9056x; 1.2523x over previous
//
#include <hip/hip_runtime.h>
#include <hip/hip_bf16.h>

#define H 128
#define NT 4
#define CAP 96
#define BK 64
#define LDK 72   // BK + 8 pad (halfs) -> 144 B stride, conflict-free

typedef __attribute__((ext_vector_type(8))) _Float16 half8;
typedef __attribute__((ext_vector_type(2))) _Float16 half2v;
typedef __attribute__((ext_vector_type(4))) float f32x4;

__device__ __forceinline__ float bf2f(unsigned short u) {
    union { unsigned int i; float f; } v;
    v.i = ((unsigned int)u) << 16;
    return v.f;
}

__device__ __forceinline__ unsigned short f2bf(float f) {
    union { float f; unsigned int i; } v;
    v.f = f;
    unsigned int x = v.i;
    unsigned int r = (x + 0x7fffu + ((x >> 16) & 1u)) >> 16;  // RNE
    return (unsigned short)r;
}

__device__ __forceinline__ float fsigmoid(float x) {
    return 1.0f / (1.0f + __expf(-x));   // x<<0 -> exp=inf -> 0 (safe)
}
__device__ __forceinline__ float ftanh(float x) {
    return 1.0f - 2.0f / (__expf(2.0f * x) + 1.0f);  // inf-safe both tails
}

// flag-adaptive fp32 read from raw input buffer (1 = bf16-packed, 0 = fp32)
__device__ __forceinline__ float readf(const void* p, long i, int isbf) {
    return isbf ? bf2f(((const unsigned short*)p)[i]) : ((const float*)p)[i];
}

// ---------------------------------------------------------------------------
// dtype detector: low u16 of each dword as bf16 exponent sanity test.
// ---------------------------------------------------------------------------
__global__ void detect_dtype(const unsigned short* __restrict__ states_u16,
                             int* __restrict__ flag) {
    __shared__ int cnt;
    if (threadIdx.x == 0) cnt = 0;
    __syncthreads();
    int local = 0;
    for (int i = threadIdx.x; i < 1024; i += 256) {
        unsigned short u = states_u16[2 * i];
        int e = (u >> 7) & 0xFF;
        if (e >= 96 && e <= 158) local++;
    }
    atomicAdd(&cnt, local);
    __syncthreads();
    if (threadIdx.x == 0) *flag = (cnt >= 512) ? 1 : 0;
}

__global__ void cast_h16(const void* __restrict__ in, _Float16* __restrict__ out,
                         const int* __restrict__ flag, int n) {
    int i = blockIdx.x * blockDim.x + threadIdx.x;
    if (i < n) out[i] = (_Float16)readf(in, i, *flag);
}

// type_W [L][t][k][c] -> BTw [L][c:128][t*128+k : 512]
__global__ void prep_BTw(const void* __restrict__ W, _Float16* __restrict__ BTw,
                         const int* __restrict__ flag, int total) {
    int i = blockIdx.x * 256 + threadIdx.x;
    if (i >= total) return;
    int l = i >> 16;            // 128*512 per layer
    int rem = i & 65535;
    int c = rem >> 9, kk = rem & 511;
    int t = kk >> 7, k = kk & 127;
    BTw[i] = (_Float16)readf(W, (((long)(l * NT + t) * H) + k) * H + c, *flag);
}

// gru kernels -> BTg2 [L][nc:512][k:256], gate-interleaved columns:
//   nc = g*64 + gate*16 + m, actual h-col c = g*16 + m, gate in {z,r,x,h}
//   z: k<128 -> gk[k][c],      k>=128 -> gr[k-128][c]
//   r: k<128 -> gk[k][128+c],  k>=128 -> gr[k-128][128+c]
//   x: k<128 -> gk[k][256+c],  else 0
//   h: k>=128 -> gr[k-128][256+c], else 0
__global__ void prep_BTg2(const void* __restrict__ gk, const void* __restrict__ gr,
                          _Float16* __restrict__ BTg, const int* __restrict__ flag,
                          int total) {
    int i = blockIdx.x * 256 + threadIdx.x;
    if (i >= total) return;
    int l = i >> 17;            // 512*256 per layer
    int rem = i & 131071;
    int nc = rem >> 8, k = rem & 255;
    int g = nc >> 6, gate = (nc >> 4) & 3, m = nc & 15;
    int c = g * 16 + m;
    int fl = *flag;
    float v = 0.0f;
    if (gate == 0) {
        v = (k < 128) ? readf(gk, ((long)l * H + k) * 384 + c, fl)
                      : readf(gr, ((long)l * H + (k - 128)) * 384 + c, fl);
    } else if (gate == 1) {
        v = (k < 128) ? readf(gk, ((long)l * H + k) * 384 + 128 + c, fl)
                      : readf(gr, ((long)l * H + (k - 128)) * 384 + 128 + c, fl);
    } else if (gate == 2) {
        if (k < 128) v = readf(gk, ((long)l * H + k) * 384 + 256 + c, fl);
    } else {
        if (k >= 128) v = readf(gr, ((long)l * H + (k - 128)) * 384 + 256 + c, fl);
    }
    BTg[i] = (_Float16)v;
}

// btab[L][t][128]=type_b; gbsum[L][256]=gb0+gb1 (z,r); gb0c/gb1c[L][128] (c-gate)
__global__ void prep_bias2(const void* __restrict__ type_b, const void* __restrict__ grub,
                           float* __restrict__ btab, float* __restrict__ gbsum,
                           float* __restrict__ gb0c, float* __restrict__ gb1c,
                           const int* __restrict__ flag, int LAYERS) {
    int i = blockIdx.x * 256 + threadIdx.x;
    int fl = *flag;
    if (i < LAYERS * NT * H) btab[i] = readf(type_b, i, fl);
    if (i < LAYERS * 256) {
        int l = i >> 8, c = i & 255;
        gbsum[i] = readf(grub, (long)l * 768 + c, fl) +
                   readf(grub, (long)l * 768 + 384 + c, fl);
    }
    if (i < LAYERS * H) {
        int l = i >> 7, c = i & 127;
        gb0c[i] = readf(grub, (long)l * 768 + 256 + c, fl);
        gb1c[i] = readf(grub, (long)l * 768 + 384 + 256 + c, fl);
    }
}

// ---------------------------------------------------------------------------
// bucket edges by dst (counts pre-zeroed by memset)
// ---------------------------------------------------------------------------
__global__ void place_edges(const int* __restrict__ edges, int* __restrict__ counts,
                            int* __restrict__ buckets, int NE) {
    int e = blockIdx.x * 256 + threadIdx.x;
    if (e >= NE) return;
    int t = edges[3 * e], src = edges[3 * e + 1], dst = edges[3 * e + 2];
    int slot = atomicAdd(&counts[dst], 1);
    if (slot < CAP) buckets[(size_t)dst * CAP + slot] = src | (t << 17);
}

// ---------------------------------------------------------------------------
// gather4: A4[node][t][:] = sum of h16[src] over in-edges of type t (fp32 acc)
// ---------------------------------------------------------------------------
__global__ __launch_bounds__(256) void gather4(
    const _Float16* __restrict__ h16, const int* __restrict__ counts,
    const int* __restrict__ buckets, _Float16* __restrict__ A4,
    int4* __restrict__ cnt4, int NN) {
    int node = blockIdx.x * 4 + (threadIdx.x >> 6);
    int lane = threadIdx.x & 63;
    if (node >= NN) return;
    int cnt = counts[node];
    if (cnt > CAP) cnt = CAP;
    const int* bkt = buckets + (size_t)node * CAP;

    float a0x = 0, a0y = 0, a1x = 0, a1y = 0;
    float a2x = 0, a2y = 0, a3x = 0, a3y = 0;
    int c0 = 0, c1 = 0, c2 = 0, c3 = 0;

#define ACC_EDGE(P, V) { int t_ = (P) >> 17;                                   \
        float vx_ = (float)(V)[0], vy_ = (float)(V)[1];                        \
        if (t_ == 0)      { a0x += vx_; a0y += vy_; c0++; }                    \
        else if (t_ == 1) { a1x += vx_; a1y += vy_; c1++; }                    \
        else if (t_ == 2) { a2x += vx_; a2y += vy_; c2++; }                    \
        else              { a3x += vx_; a3y += vy_; c3++; } }

    int e = 0;
    for (; e + 4 <= cnt; e += 4) {
        int4 p4 = *(const int4*)&bkt[e];
        half2v v0 = *(const half2v*)&h16[(size_t)(p4.x & 0x1FFFF) * H + lane * 2];
        half2v v1 = *(const half2v*)&h16[(size_t)(p4.y & 0x1FFFF) * H + lane * 2];
        half2v v2 = *(const half2v*)&h16[(size_t)(p4.z & 0x1FFFF) * H + lane * 2];
        half2v v3 = *(const half2v*)&h16[(size_t)(p4.w & 0x1FFFF) * H + lane * 2];
        ACC_EDGE(p4.x, v0); ACC_EDGE(p4.y, v1);
        ACC_EDGE(p4.z, v2); ACC_EDGE(p4.w, v3);
    }
    for (; e < cnt; e++) {
        int p = bkt[e];
        half2v v = *(const half2v*)&h16[(size_t)(p & 0x1FFFF) * H + lane * 2];
        ACC_EDGE(p, v);
    }
#undef ACC_EDGE

    half2v o;
    size_t base = (size_t)node * 4 * H + lane * 2;
    o[0] = (_Float16)a0x; o[1] = (_Float16)a0y; *(half2v*)&A4[base] = o;
    o[0] = (_Float16)a1x; o[1] = (_Float16)a1y; *(half2v*)&A4[base + H] = o;
    o[0] = (_Float16)a2x; o[1] = (_Float16)a2y; *(half2v*)&A4[base + 2 * H] = o;
    o[0] = (_Float16)a3x; o[1] = (_Float16)a3y; *(half2v*)&A4[base + 3 * H] = o;
    if (lane == 0) cnt4[node] = make_int4(c0, c1, c2, c3);
}

// ---------------------------------------------------------------------------
// agg GEMM: agg[row][c] = sum_k A4[row][k] * BTw[c][k] + cnt-weighted bias
// Block 128x128, K=512 (8 chunks of 64), 4 waves each 64x64.
// ---------------------------------------------------------------------------
__global__ __launch_bounds__(256) void gemm_agg(
    const _Float16* __restrict__ A4,    // [NN][512]
    const _Float16* __restrict__ BT,    // [128c][512k]
    _Float16* __restrict__ agg,         // [NN][128]
    const int4* __restrict__ cnt4, const float* __restrict__ btab,
    int Mrows) {
    __shared__ _Float16 As[128 * LDK];
    __shared__ _Float16 Bs[128 * LDK];

    const int row0 = blockIdx.x * 128;
    const int tid = threadIdx.x;
    const int wave = tid >> 6, lane = tid & 63;
    const int m = lane & 15, quad = lane >> 4;
    const int wr = (wave & 1) * 64, wc = (wave >> 1) * 64;

    f32x4 acc[4][4] = {};

    for (int kc = 0; kc < 8; kc++) {
        const int k0 = kc * BK;
        __syncthreads();
#pragma unroll
        for (int p = 0; p < 4; p++) {          // A tile 128 x 64
            int idx = p * 256 + tid;
            int r = idx >> 3, k8 = (idx & 7) * 8;
            int rg = row0 + r;
            if (rg >= Mrows) rg = Mrows - 1;
            *(half8*)&As[r * LDK + k8] = *(const half8*)&A4[(size_t)rg * 512 + k0 + k8];
        }
#pragma unroll
        for (int p = 0; p < 4; p++) {          // B tile 128 x 64
            int idx = p * 256 + tid;
            int c = idx >> 3, k8 = (idx & 7) * 8;
            *(half8*)&Bs[c * LDK + k8] = *(const half8*)&BT[(size_t)c * 512 + k0 + k8];
        }
        __syncthreads();

#pragma unroll
        for (int ks = 0; ks < 2; ks++) {
            half8 a[4], b[4];
#pragma unroll
            for (int mt = 0; mt < 4; mt++)
                a[mt] = *(const half8*)&As[(wr + mt * 16 + m) * LDK + ks * 32 + quad * 8];
#pragma unroll
            for (int nt = 0; nt < 4; nt++)
                b[nt] = *(const half8*)&Bs[(wc + nt * 16 + m) * LDK + ks * 32 + quad * 8];
#pragma unroll
            for (int mt = 0; mt < 4; mt++)
#pragma unroll
                for (int nt = 0; nt < 4; nt++)
                    acc[mt][nt] = __builtin_amdgcn_mfma_f32_16x16x32_f16(
                        a[mt], b[nt], acc[mt][nt], 0, 0, 0);
        }
    }

#pragma unroll
    for (int mt = 0; mt < 4; mt++) {
#pragma unroll
        for (int i = 0; i < 4; i++) {
            int row = row0 + wr + mt * 16 + quad * 4 + i;
            if (row >= Mrows) continue;
            int4 c4 = cnt4[row];
#pragma unroll
            for (int nt = 0; nt < 4; nt++) {
                int cl = wc + nt * 16 + m;
                float bias = c4.x * btab[cl] + c4.y * btab[128 + cl] +
                             c4.z * btab[256 + cl] + c4.w * btab[384 + cl];
                agg[(size_t)row * H + cl] = (_Float16)(acc[mt][nt][i] + bias);
            }
        }
    }
}

// ---------------------------------------------------------------------------
// GRU GEMM with fused gate epilogue.
// A = [agg(K 0..127) | h(K 128..255)], B = BTg2 (gate-interleaved cols).
// Block 128 rows x 128 B-cols; wave tile 64x64 covers ONE col-group g:
//   nt=0:z, nt=1:r, nt=2:xh, nt=3:hh, all for h-col c = g*16 + m.
// Epilogue computes z,r,c,h' in registers; writes hnext (and final out).
// ---------------------------------------------------------------------------
__global__ __launch_bounds__(256) void gru_gemm_gate(
    const _Float16* __restrict__ agg16,  // [NN][128]
    const _Float16* __restrict__ h16,    // [NN][128]
    const _Float16* __restrict__ BT,     // [512nc][256k]
    const float* __restrict__ gbsum,     // [256]
    const float* __restrict__ gb0c,      // [128]
    const float* __restrict__ gb1c,      // [128]
    _Float16* __restrict__ hnext,        // [NN][128]
    void* __restrict__ outbuf,           // final output or nullptr
    const int* __restrict__ flag, int NN) {
    __shared__ _Float16 As[128 * LDK];
    __shared__ _Float16 Bs[128 * LDK];

    const int row0 = blockIdx.x * 128;
    const int col0 = blockIdx.y * 128;
    const int tid = threadIdx.x;
    const int wave = tid >> 6, lane = tid & 63;
    const int m = lane & 15, quad = lane >> 4;
    const int wr = (wave & 1) * 64, wc = (wave >> 1) * 64;

    f32x4 acc[4][4] = {};

    for (int kc = 0; kc < 4; kc++) {
        const int k0 = kc * BK;
        const _Float16* Ap = (k0 < 128) ? agg16 : h16;
        const int kof = k0 & 127;

        __syncthreads();
#pragma unroll
        for (int p = 0; p < 4; p++) {          // A tile 128 x 64
            int idx = p * 256 + tid;
            int r = idx >> 3, k8 = (idx & 7) * 8;
            int rg = row0 + r;
            if (rg >= NN) rg = NN - 1;
            *(half8*)&As[r * LDK + k8] = *(const half8*)&Ap[(size_t)rg * H + kof + k8];
        }
#pragma unroll
        for (int p = 0; p < 4; p++) {          // B tile 128 x 64
            int idx = p * 256 + tid;
            int c = idx >> 3, k8 = (idx & 7) * 8;
            *(half8*)&Bs[c * LDK + k8] = *(const half8*)&BT[(size_t)(col0 + c) * 256 + k0 + k8];
        }
        __syncthreads();

#pragma unroll
        for (int ks = 0; ks < 2; ks++) {
            half8 a[4], b[4];
#pragma unroll
            for (int mt = 0; mt < 4; mt++)
                a[mt] = *(const half8*)&As[(wr + mt * 16 + m) * LDK + ks * 32 + quad * 8];
#pragma unroll
            for (int nt = 0; nt < 4; nt++)
                b[nt] = *(const half8*)&Bs[(wc + nt * 16 + m) * LDK + ks * 32 + quad * 8];
#pragma unroll
            for (int mt = 0; mt < 4; mt++)
#pragma unroll
                for (int nt = 0; nt < 4; nt++)
                    acc[mt][nt] = __builtin_amdgcn_mfma_f32_16x16x32_f16(
                        a[mt], b[nt], acc[mt][nt], 0, 0, 0);
        }
    }

    // gate epilogue: this wave's col-group
    const int g = (col0 + wc) >> 6;      // 0..7
    const int c = g * 16 + m;            // h-column
    const float bz = gbsum[c];
    const float br = gbsum[128 + c];
    const float bx = gb0c[c];
    const float bh = gb1c[c];
    const int fl = outbuf ? *flag : 0;

#pragma unroll
    for (int mt = 0; mt < 4; mt++) {
#pragma unroll
        for (int i = 0; i < 4; i++) {
            int row = row0 + wr + mt * 16 + quad * 4 + i;
            if (row >= NN) continue;
            float z = fsigmoid(acc[mt][0][i] + bz);
            float r = fsigmoid(acc[mt][1][i] + br);
            float cc = ftanh((acc[mt][2][i] + bx) + r * (acc[mt][3][i] + bh));
            float hv = (float)h16[(size_t)row * H + c];
            float hn = z * hv + (1.0f - z) * cc;
            size_t oi = (size_t)row * H + c;
            hnext[oi] = (_Float16)hn;
            if (outbuf) {
                if (fl) ((unsigned short*)outbuf)[oi] = f2bf(hn);
                else    ((float*)outbuf)[oi] = hn;
            }
        }
    }
}

// ---------------------------------------------------------------------------
extern "C" void kernel_launch(void* const* d_in, const int* in_sizes, int n_in,
                              void* d_out, int out_size, void* d_ws, size_t ws_size,
                              hipStream_t stream) {
    const void* states = d_in[0];
    const int*  edges  = (const int*)d_in[1];
    const void* type_W = d_in[2];
    const void* type_b = d_in[3];
    const void* gruk   = d_in[4];
    const void* grur   = d_in[5];
    const void* grub   = d_in[6];

    const int NN = in_sizes[0] / H;    // 50000
    const int NE = in_sizes[1] / 3;    // 400000
    const int nW = in_sizes[2];        // L*NT*128*128
    const int LAYERS = nW / (NT * H * H);

    // --- workspace layout ---
    char* w = (char*)d_ws;
    int* flag = (int*)w;                               w += 64;
    _Float16* h16A  = (_Float16*)w;                    w += (size_t)NN * H * 2;
    _Float16* h16B  = (_Float16*)w;                    w += (size_t)NN * H * 2;
    _Float16* agg16 = (_Float16*)w;                    w += (size_t)NN * H * 2;
    _Float16* A4    = (_Float16*)w;                    w += (size_t)NN * 4 * H * 2;
    _Float16* BTw = (_Float16*)w;                      w += (size_t)LAYERS * H * 512 * 2;
    _Float16* BTg = (_Float16*)w;                      w += (size_t)LAYERS * 512 * 256 * 2;
    float* btab  = (float*)w;                          w += (size_t)LAYERS * NT * H * 4;
    float* gbsum = (float*)w;                          w += (size_t)LAYERS * 256 * 4;
    float* gb0c  = (float*)w;                          w += (size_t)LAYERS * H * 4;
    float* gb1c  = (float*)w;                          w += (size_t)LAYERS * H * 4;
    int* counts  = (int*)w;                            w += (size_t)NN * 4;
    int4* cnt4   = (int4*)w;                           w += (size_t)NN * 16;
    int* buckets = (int*)w;                            // [NN][CAP]

    detect_dtype<<<1, 256, 0, stream>>>((const unsigned short*)states, flag);

    cast_h16<<<(NN * H + 255) / 256, 256, 0, stream>>>(states, h16A, flag, NN * H);
    prep_BTw<<<(LAYERS * 65536 + 255) / 256, 256, 0, stream>>>(type_W, BTw, flag,
                                                               LAYERS * 65536);
    prep_BTg2<<<(LAYERS * 131072 + 255) / 256, 256, 0, stream>>>(gruk, grur, BTg, flag,
                                                                 LAYERS * 131072);
    prep_bias2<<<4, 256, 0, stream>>>(type_b, grub, btab, gbsum, gb0c, gb1c, flag, LAYERS);

    hipMemsetAsync(counts, 0, (size_t)NN * 4, stream);
    place_edges<<<(NE + 255) / 256, 256, 0, stream>>>(edges, counts, buckets, NE);

    const int rtiles = (NN + 127) / 128;
    for (int L = 0; L < LAYERS; L++) {
        const _Float16* hcur = (L & 1) ? h16B : h16A;
        _Float16* hnext      = (L & 1) ? h16A : h16B;

        gather4<<<(NN + 3) / 4, 256, 0, stream>>>(hcur, counts, buckets, A4, cnt4, NN);

        gemm_agg<<<rtiles, 256, 0, stream>>>(
            A4, BTw + (size_t)L * H * 512, agg16,
            cnt4, btab + (size_t)L * NT * H, NN);

        gru_gemm_gate<<<dim3(rtiles, 4), 256, 0, stream>>>(
            agg16, hcur,
            BTg + (size_t)L * 512 * 256,
            gbsum + (size_t)L * 256, gb0c + (size_t)L * H, gb1c + (size_t)L * H,
            hnext, (L == LAYERS - 1) ? d_out : nullptr, flag, NN);
    }
}

// Round 7
// 322.279 us; speedup vs baseline: 1.9297x; 1.0126x over previous
//
#include <hip/hip_runtime.h>
#include <hip/hip_bf16.h>

#define H 128
#define NT 4
#define CAP 96
#define BK 64

typedef __attribute__((ext_vector_type(8))) _Float16 half8;
typedef __attribute__((ext_vector_type(2))) _Float16 half2v;
typedef __attribute__((ext_vector_type(4))) float f32x4;

#if defined(__has_builtin)
#if __has_builtin(__builtin_amdgcn_global_load_lds)
#define HAS_GLL 1
#endif
#endif
#ifndef HAS_GLL
#define HAS_GLL 0
#endif

__device__ __forceinline__ float bf2f(unsigned short u) {
    union { unsigned int i; float f; } v;
    v.i = ((unsigned int)u) << 16;
    return v.f;
}

__device__ __forceinline__ unsigned short f2bf(float f) {
    union { float f; unsigned int i; } v;
    v.f = f;
    unsigned int x = v.i;
    unsigned int r = (x + 0x7fffu + ((x >> 16) & 1u)) >> 16;  // RNE
    return (unsigned short)r;
}

__device__ __forceinline__ float fsigmoid(float x) {
    return 1.0f / (1.0f + __expf(-x));
}
__device__ __forceinline__ float ftanh(float x) {
    return 1.0f - 2.0f / (__expf(2.0f * x) + 1.0f);  // inf-safe both tails
}

// flag-adaptive fp32 read from raw input buffer (1 = bf16-packed, 0 = fp32)
__device__ __forceinline__ float readf(const void* p, long i, int isbf) {
    return isbf ? bf2f(((const unsigned short*)p)[i]) : ((const float*)p)[i];
}

// ---------------------------------------------------------------------------
// async global->LDS 16B (direct-to-LDS DMA; dest = wave-uniform base + lane*16)
// ---------------------------------------------------------------------------
__device__ __forceinline__ void gll16(const _Float16* g, _Float16* l) {
#if HAS_GLL
    __builtin_amdgcn_global_load_lds(
        (const __attribute__((address_space(1))) unsigned int*)g,
        (__attribute__((address_space(3))) unsigned int*)l, 16, 0, 0);
#endif
}

// ---------------------------------------------------------------------------
// Stage a 128row x 64k fp16 tile into LDS, unpadded (row stride 64 halfs),
// XOR-swizzled: LDS[r][chunk p] holds global chunk (p ^ (r&7)).
// 4 waves x 4 ops x (64 lanes * 16B) = 16 KB.
// ---------------------------------------------------------------------------
__device__ __forceinline__ void stage_tile(
    const _Float16* __restrict__ gbase, int rstride, int row0, int kof,
    int maxrow, _Float16* lds) {
    const int wave = threadIdx.x >> 6, lane = threadIdx.x & 63;
#pragma unroll
    for (int s = 0; s < 4; s++) {
        int R = wave * 32 + s * 8;               // 8-row group (8-aligned)
        int rl = R + (lane >> 3);
        int rg = row0 + rl;
        if (rg >= maxrow) rg = maxrow - 1;
        int chunk = (lane & 7) ^ (rl & 7);
        const _Float16* gp = gbase + (size_t)rg * rstride + kof + chunk * 8;
#if HAS_GLL
        gll16(gp, lds + R * 64);
#else
        *(half8*)&lds[rl * 64 + (lane & 7) * 8] = *(const half8*)gp;
#endif
    }
}

// fragment read honoring the swizzle: global chunk g (=ks*4+quad) of row r
__device__ __forceinline__ half8 frag(const _Float16* lds, int r, int g) {
    return *(const half8*)&lds[r * 64 + ((g ^ (r & 7)) * 8)];
}

// ---------------------------------------------------------------------------
// dtype detector: low u16 of each dword as bf16 exponent sanity test.
// ---------------------------------------------------------------------------
__global__ void detect_dtype(const unsigned short* __restrict__ states_u16,
                             int* __restrict__ flag) {
    __shared__ int cnt;
    if (threadIdx.x == 0) cnt = 0;
    __syncthreads();
    int local = 0;
    for (int i = threadIdx.x; i < 1024; i += 256) {
        unsigned short u = states_u16[2 * i];
        int e = (u >> 7) & 0xFF;
        if (e >= 96 && e <= 158) local++;
    }
    atomicAdd(&cnt, local);
    __syncthreads();
    if (threadIdx.x == 0) *flag = (cnt >= 512) ? 1 : 0;
}

__global__ void cast_h16(const void* __restrict__ in, _Float16* __restrict__ out,
                         const int* __restrict__ flag, int n) {
    int i = blockIdx.x * blockDim.x + threadIdx.x;
    if (i < n) out[i] = (_Float16)readf(in, i, *flag);
}

// type_W [L][t][k][c] -> BTw [L][c:128][t*128+k : 512]
__global__ void prep_BTw(const void* __restrict__ W, _Float16* __restrict__ BTw,
                         const int* __restrict__ flag, int total) {
    int i = blockIdx.x * 256 + threadIdx.x;
    if (i >= total) return;
    int l = i >> 16;            // 128*512 per layer
    int rem = i & 65535;
    int c = rem >> 9, kk = rem & 511;
    int t = kk >> 7, k = kk & 127;
    BTw[i] = (_Float16)readf(W, (((long)(l * NT + t) * H) + k) * H + c, *flag);
}

// gru kernels -> BTg2 [L][nc:512][k:256], gate-interleaved columns:
//   nc = g*64 + gate*16 + m, actual h-col c = g*16 + m, gate in {z,r,x,h}
__global__ void prep_BTg2(const void* __restrict__ gk, const void* __restrict__ gr,
                          _Float16* __restrict__ BTg, const int* __restrict__ flag,
                          int total) {
    int i = blockIdx.x * 256 + threadIdx.x;
    if (i >= total) return;
    int l = i >> 17;            // 512*256 per layer
    int rem = i & 131071;
    int nc = rem >> 8, k = rem & 255;
    int g = nc >> 6, gate = (nc >> 4) & 3, m = nc & 15;
    int c = g * 16 + m;
    int fl = *flag;
    float v = 0.0f;
    if (gate == 0) {
        v = (k < 128) ? readf(gk, ((long)l * H + k) * 384 + c, fl)
                      : readf(gr, ((long)l * H + (k - 128)) * 384 + c, fl);
    } else if (gate == 1) {
        v = (k < 128) ? readf(gk, ((long)l * H + k) * 384 + 128 + c, fl)
                      : readf(gr, ((long)l * H + (k - 128)) * 384 + 128 + c, fl);
    } else if (gate == 2) {
        if (k < 128) v = readf(gk, ((long)l * H + k) * 384 + 256 + c, fl);
    } else {
        if (k >= 128) v = readf(gr, ((long)l * H + (k - 128)) * 384 + 256 + c, fl);
    }
    BTg[i] = (_Float16)v;
}

// btab[L][t][128]=type_b; gbsum[L][256]=gb0+gb1 (z,r); gb0c/gb1c[L][128] (c-gate)
__global__ void prep_bias2(const void* __restrict__ type_b, const void* __restrict__ grub,
                           float* __restrict__ btab, float* __restrict__ gbsum,
                           float* __restrict__ gb0c, float* __restrict__ gb1c,
                           const int* __restrict__ flag, int LAYERS) {
    int i = blockIdx.x * 256 + threadIdx.x;
    int fl = *flag;
    if (i < LAYERS * NT * H) btab[i] = readf(type_b, i, fl);
    if (i < LAYERS * 256) {
        int l = i >> 8, c = i & 255;
        gbsum[i] = readf(grub, (long)l * 768 + c, fl) +
                   readf(grub, (long)l * 768 + 384 + c, fl);
    }
    if (i < LAYERS * H) {
        int l = i >> 7, c = i & 127;
        gb0c[i] = readf(grub, (long)l * 768 + 256 + c, fl);
        gb1c[i] = readf(grub, (long)l * 768 + 384 + 256 + c, fl);
    }
}

// ---------------------------------------------------------------------------
// bucket edges by dst (counts pre-zeroed by memset)
// ---------------------------------------------------------------------------
__global__ void place_edges(const int* __restrict__ edges, int* __restrict__ counts,
                            int* __restrict__ buckets, int NE) {
    int e = blockIdx.x * 256 + threadIdx.x;
    if (e >= NE) return;
    int t = edges[3 * e], src = edges[3 * e + 1], dst = edges[3 * e + 2];
    int slot = atomicAdd(&counts[dst], 1);
    if (slot < CAP) buckets[(size_t)dst * CAP + slot] = src | (t << 17);
}

// ---------------------------------------------------------------------------
// gather4: A4[node][t][:] = sum of h16[src] over in-edges of type t (fp32 acc)
// ---------------------------------------------------------------------------
__global__ __launch_bounds__(256) void gather4(
    const _Float16* __restrict__ h16, const int* __restrict__ counts,
    const int* __restrict__ buckets, _Float16* __restrict__ A4,
    int4* __restrict__ cnt4, int NN) {
    int node = blockIdx.x * 4 + (threadIdx.x >> 6);
    int lane = threadIdx.x & 63;
    if (node >= NN) return;
    int cnt = counts[node];
    if (cnt > CAP) cnt = CAP;
    const int* bkt = buckets + (size_t)node * CAP;

    float a0x = 0, a0y = 0, a1x = 0, a1y = 0;
    float a2x = 0, a2y = 0, a3x = 0, a3y = 0;
    int c0 = 0, c1 = 0, c2 = 0, c3 = 0;

#define ACC_EDGE(P, V) { int t_ = (P) >> 17;                                   \
        float vx_ = (float)(V)[0], vy_ = (float)(V)[1];                        \
        if (t_ == 0)      { a0x += vx_; a0y += vy_; c0++; }                    \
        else if (t_ == 1) { a1x += vx_; a1y += vy_; c1++; }                    \
        else if (t_ == 2) { a2x += vx_; a2y += vy_; c2++; }                    \
        else              { a3x += vx_; a3y += vy_; c3++; } }

    int e = 0;
    for (; e + 4 <= cnt; e += 4) {
        int4 p4 = *(const int4*)&bkt[e];
        half2v v0 = *(const half2v*)&h16[(size_t)(p4.x & 0x1FFFF) * H + lane * 2];
        half2v v1 = *(const half2v*)&h16[(size_t)(p4.y & 0x1FFFF) * H + lane * 2];
        half2v v2 = *(const half2v*)&h16[(size_t)(p4.z & 0x1FFFF) * H + lane * 2];
        half2v v3 = *(const half2v*)&h16[(size_t)(p4.w & 0x1FFFF) * H + lane * 2];
        ACC_EDGE(p4.x, v0); ACC_EDGE(p4.y, v1);
        ACC_EDGE(p4.z, v2); ACC_EDGE(p4.w, v3);
    }
    for (; e < cnt; e++) {
        int p = bkt[e];
        half2v v = *(const half2v*)&h16[(size_t)(p & 0x1FFFF) * H + lane * 2];
        ACC_EDGE(p, v);
    }
#undef ACC_EDGE

    half2v o;
    size_t base = (size_t)node * 4 * H + lane * 2;
    o[0] = (_Float16)a0x; o[1] = (_Float16)a0y; *(half2v*)&A4[base] = o;
    o[0] = (_Float16)a1x; o[1] = (_Float16)a1y; *(half2v*)&A4[base + H] = o;
    o[0] = (_Float16)a2x; o[1] = (_Float16)a2y; *(half2v*)&A4[base + 2 * H] = o;
    o[0] = (_Float16)a3x; o[1] = (_Float16)a3y; *(half2v*)&A4[base + 3 * H] = o;
    if (lane == 0) cnt4[node] = make_int4(c0, c1, c2, c3);
}

// ---------------------------------------------------------------------------
// agg GEMM: agg[row][c] = sum_k A4[row][k] * BTw[c][k] + cnt-weighted bias
// Block 128x128, K=512 (8 chunks of 64), 4 waves each 64x64.
// global_load_lds staging, XOR-swizzled unpadded LDS.
// ---------------------------------------------------------------------------
__global__ __launch_bounds__(256) void gemm_agg(
    const _Float16* __restrict__ A4,    // [NN][512]
    const _Float16* __restrict__ BT,    // [128c][512k]
    _Float16* __restrict__ agg,         // [NN][128]
    const int4* __restrict__ cnt4, const float* __restrict__ btab,
    int Mrows) {
    __shared__ _Float16 As[128 * 64];
    __shared__ _Float16 Bs[128 * 64];

    const int row0 = blockIdx.x * 128;
    const int tid = threadIdx.x;
    const int wave = tid >> 6, lane = tid & 63;
    const int m = lane & 15, quad = lane >> 4;
    const int wr = (wave & 1) * 64, wc = (wave >> 1) * 64;

    f32x4 acc[4][4] = {};

    for (int kc = 0; kc < 8; kc++) {
        const int k0 = kc * BK;
        __syncthreads();
        stage_tile(A4, 512, row0, k0, Mrows, As);
        stage_tile(BT, 512, 0, k0, 128, Bs);
        __syncthreads();

#pragma unroll
        for (int ks = 0; ks < 2; ks++) {
            half8 a[4], b[4];
#pragma unroll
            for (int mt = 0; mt < 4; mt++)
                a[mt] = frag(As, wr + mt * 16 + m, ks * 4 + quad);
#pragma unroll
            for (int nt = 0; nt < 4; nt++)
                b[nt] = frag(Bs, wc + nt * 16 + m, ks * 4 + quad);
#pragma unroll
            for (int mt = 0; mt < 4; mt++)
#pragma unroll
                for (int nt = 0; nt < 4; nt++)
                    acc[mt][nt] = __builtin_amdgcn_mfma_f32_16x16x32_f16(
                        a[mt], b[nt], acc[mt][nt], 0, 0, 0);
        }
    }

#pragma unroll
    for (int mt = 0; mt < 4; mt++) {
#pragma unroll
        for (int i = 0; i < 4; i++) {
            int row = row0 + wr + mt * 16 + quad * 4 + i;
            if (row >= Mrows) continue;
            int4 c4 = cnt4[row];
#pragma unroll
            for (int nt = 0; nt < 4; nt++) {
                int cl = wc + nt * 16 + m;
                float bias = c4.x * btab[cl] + c4.y * btab[128 + cl] +
                             c4.z * btab[256 + cl] + c4.w * btab[384 + cl];
                agg[(size_t)row * H + cl] = (_Float16)(acc[mt][nt][i] + bias);
            }
        }
    }
}

// ---------------------------------------------------------------------------
// GRU GEMM with fused gate epilogue.
// A = [agg(K 0..127) | h(K 128..255)], B = BTg2 (gate-interleaved cols).
// Block 128 rows x 128 B-cols; wave tile 64x64 covers ONE col-group g:
//   nt=0:z, nt=1:r, nt=2:xh, nt=3:hh, all for h-col c = g*16 + m.
// h for the gate blend is staged in LDS (32 cols per block, coalesced).
// ---------------------------------------------------------------------------
__global__ __launch_bounds__(256) void gru_gemm_gate(
    const _Float16* __restrict__ agg16,  // [NN][128]
    const _Float16* __restrict__ h16,    // [NN][128]
    const _Float16* __restrict__ BT,     // [512nc][256k]
    const float* __restrict__ gbsum,     // [256]
    const float* __restrict__ gb0c,      // [128]
    const float* __restrict__ gb1c,      // [128]
    _Float16* __restrict__ hnext,        // [NN][128]
    void* __restrict__ outbuf,           // final output or nullptr
    const int* __restrict__ flag, int NN) {
    __shared__ _Float16 As[128 * 64];
    __shared__ _Float16 Bs[128 * 64];
    __shared__ _Float16 hg[128 * 32];    // h cols [32y, 32y+32) for gate blend

    const int row0 = blockIdx.x * 128;
    const int y = blockIdx.y;
    const int col0 = y * 128;
    const int tid = threadIdx.x;
    const int wave = tid >> 6, lane = tid & 63;
    const int m = lane & 15, quad = lane >> 4;
    const int wr = (wave & 1) * 64, wc = (wave >> 1) * 64;

    f32x4 acc[4][4] = {};

    for (int kc = 0; kc < 4; kc++) {
        const int k0 = kc * BK;
        __syncthreads();
        if (kc < 2) stage_tile(agg16, H, row0, k0, NN, As);
        else        stage_tile(h16, H, row0, k0 - 128, NN, As);
        stage_tile(BT, 256, col0, k0, 512, Bs);
        if (kc == 0) {
#pragma unroll
            for (int s = 0; s < 2; s++) {       // hg: 128 rows x 32 cols
                int idx = s * 256 + tid;        // 0..511 segments of 8 halfs
                int r = idx >> 2, cseg = (idx & 3) * 8;
                int rg = row0 + r;
                if (rg >= NN) rg = NN - 1;
                *(half8*)&hg[r * 32 + cseg] =
                    *(const half8*)&h16[(size_t)rg * H + y * 32 + cseg];
            }
        }
        __syncthreads();

#pragma unroll
        for (int ks = 0; ks < 2; ks++) {
            half8 a[4], b[4];
#pragma unroll
            for (int mt = 0; mt < 4; mt++)
                a[mt] = frag(As, wr + mt * 16 + m, ks * 4 + quad);
#pragma unroll
            for (int nt = 0; nt < 4; nt++)
                b[nt] = frag(Bs, wc + nt * 16 + m, ks * 4 + quad);
#pragma unroll
            for (int mt = 0; mt < 4; mt++)
#pragma unroll
                for (int nt = 0; nt < 4; nt++)
                    acc[mt][nt] = __builtin_amdgcn_mfma_f32_16x16x32_f16(
                        a[mt], b[nt], acc[mt][nt], 0, 0, 0);
        }
    }

    // gate epilogue: this wave's col-group
    const int g = (col0 + wc) >> 6;      // 0..7
    const int c = g * 16 + m;            // h-column
    const int chg = (wc >> 2) + m;       // c - 32y = (wc/64)*16 + m
    const float bz = gbsum[c];
    const float br = gbsum[128 + c];
    const float bx = gb0c[c];
    const float bh = gb1c[c];
    const int fl = outbuf ? *flag : 0;

#pragma unroll
    for (int mt = 0; mt < 4; mt++) {
#pragma unroll
        for (int i = 0; i < 4; i++) {
            int rl = wr + mt * 16 + quad * 4 + i;
            int row = row0 + rl;
            if (row >= NN) continue;
            float z = fsigmoid(acc[mt][0][i] + bz);
            float r = fsigmoid(acc[mt][1][i] + br);
            float cc = ftanh((acc[mt][2][i] + bx) + r * (acc[mt][3][i] + bh));
            float hv = (float)hg[rl * 32 + chg];
            float hn = z * hv + (1.0f - z) * cc;
            size_t oi = (size_t)row * H + c;
            hnext[oi] = (_Float16)hn;
            if (outbuf) {
                if (fl) ((unsigned short*)outbuf)[oi] = f2bf(hn);
                else    ((float*)outbuf)[oi] = hn;
            }
        }
    }
}

// ---------------------------------------------------------------------------
extern "C" void kernel_launch(void* const* d_in, const int* in_sizes, int n_in,
                              void* d_out, int out_size, void* d_ws, size_t ws_size,
                              hipStream_t stream) {
    const void* states = d_in[0];
    const int*  edges  = (const int*)d_in[1];
    const void* type_W = d_in[2];
    const void* type_b = d_in[3];
    const void* gruk   = d_in[4];
    const void* grur   = d_in[5];
    const void* grub   = d_in[6];

    const int NN = in_sizes[0] / H;    // 50000
    const int NE = in_sizes[1] / 3;    // 400000
    const int nW = in_sizes[2];        // L*NT*128*128
    const int LAYERS = nW / (NT * H * H);

    // --- workspace layout ---
    char* w = (char*)d_ws;
    int* flag = (int*)w;                               w += 64;
    _Float16* h16A  = (_Float16*)w;                    w += (size_t)NN * H * 2;
    _Float16* h16B  = (_Float16*)w;                    w += (size_t)NN * H * 2;
    _Float16* agg16 = (_Float16*)w;                    w += (size_t)NN * H * 2;
    _Float16* A4    = (_Float16*)w;                    w += (size_t)NN * 4 * H * 2;
    _Float16* BTw = (_Float16*)w;                      w += (size_t)LAYERS * H * 512 * 2;
    _Float16* BTg = (_Float16*)w;                      w += (size_t)LAYERS * 512 * 256 * 2;
    float* btab  = (float*)w;                          w += (size_t)LAYERS * NT * H * 4;
    float* gbsum = (float*)w;                          w += (size_t)LAYERS * 256 * 4;
    float* gb0c  = (float*)w;                          w += (size_t)LAYERS * H * 4;
    float* gb1c  = (float*)w;                          w += (size_t)LAYERS * H * 4;
    int* counts  = (int*)w;                            w += (size_t)NN * 4;
    int4* cnt4   = (int4*)w;                           w += (size_t)NN * 16;
    int* buckets = (int*)w;                            // [NN][CAP]

    detect_dtype<<<1, 256, 0, stream>>>((const unsigned short*)states, flag);

    cast_h16<<<(NN * H + 255) / 256, 256, 0, stream>>>(states, h16A, flag, NN * H);
    prep_BTw<<<(LAYERS * 65536 + 255) / 256, 256, 0, stream>>>(type_W, BTw, flag,
                                                               LAYERS * 65536);
    prep_BTg2<<<(LAYERS * 131072 + 255) / 256, 256, 0, stream>>>(gruk, grur, BTg, flag,
                                                                 LAYERS * 131072);
    prep_bias2<<<4, 256, 0, stream>>>(type_b, grub, btab, gbsum, gb0c, gb1c, flag, LAYERS);

    hipMemsetAsync(counts, 0, (size_t)NN * 4, stream);
    place_edges<<<(NE + 255) / 256, 256, 0, stream>>>(edges, counts, buckets, NE);

    const int rtiles = (NN + 127) / 128;
    for (int L = 0; L < LAYERS; L++) {
        const _Float16* hcur = (L & 1) ? h16B : h16A;
        _Float16* hnext      = (L & 1) ? h16A : h16B;

        gather4<<<(NN + 3) / 4, 256, 0, stream>>>(hcur, counts, buckets, A4, cnt4, NN);

        gemm_agg<<<rtiles, 256, 0, stream>>>(
            A4, BTw + (size_t)L * H * 512, agg16,
            cnt4, btab + (size_t)L * NT * H, NN);

        gru_gemm_gate<<<dim3(rtiles, 4), 256, 0, stream>>>(
            agg16, hcur,
            BTg + (size_t)L * 512 * 256,
            gbsum + (size_t)L * 256, gb0c + (size_t)L * H, gb1c + (size_t)L * H,
            hnext, (L == LAYERS - 1) ? d_out : nullptr, flag, NN);
    }
}

// Round 8
// 300.063 us; speedup vs baseline: 2.0725x; 1.0740x over previous
//
#include <hip/hip_runtime.h>
#include <hip/hip_bf16.h>

#define H 128
#define NT 4
#define CAP4 40
#define BK 64

typedef __attribute__((ext_vector_type(8))) _Float16 half8;
typedef __attribute__((ext_vector_type(4))) float f32x4;

#if defined(__has_builtin)
#if __has_builtin(__builtin_amdgcn_global_load_lds)
#define HAS_GLL 1
#endif
#endif
#ifndef HAS_GLL
#define HAS_GLL 0
#endif

__device__ __forceinline__ float bf2f(unsigned short u) {
    union { unsigned int i; float f; } v;
    v.i = ((unsigned int)u) << 16;
    return v.f;
}

__device__ __forceinline__ unsigned short f2bf(float f) {
    union { float f; unsigned int i; } v;
    v.f = f;
    unsigned int x = v.i;
    unsigned int r = (x + 0x7fffu + ((x >> 16) & 1u)) >> 16;  // RNE
    return (unsigned short)r;
}

__device__ __forceinline__ float fsigmoid(float x) {
    return 1.0f / (1.0f + __expf(-x));
}
__device__ __forceinline__ float ftanh(float x) {
    return 1.0f - 2.0f / (__expf(2.0f * x) + 1.0f);  // inf-safe both tails
}

// flag-adaptive fp32 read from raw input buffer (1 = bf16-packed, 0 = fp32)
__device__ __forceinline__ float readf(const void* p, long i, int isbf) {
    return isbf ? bf2f(((const unsigned short*)p)[i]) : ((const float*)p)[i];
}

// ---------------------------------------------------------------------------
// async global->LDS 16B
// ---------------------------------------------------------------------------
__device__ __forceinline__ void gll16(const _Float16* g, _Float16* l) {
#if HAS_GLL
    __builtin_amdgcn_global_load_lds(
        (const __attribute__((address_space(1))) unsigned int*)g,
        (__attribute__((address_space(3))) unsigned int*)l, 16, 0, 0);
#endif
}

// ---------------------------------------------------------------------------
// Stage a 128row x 64k fp16 tile into LDS, unpadded (row stride 64 halfs),
// XOR-swizzled: LDS[r][chunk p] holds global chunk (p ^ (r&7)).
// ---------------------------------------------------------------------------
__device__ __forceinline__ void stage_tile(
    const _Float16* __restrict__ gbase, int rstride, int row0, int kof,
    int maxrow, _Float16* lds) {
    const int wave = threadIdx.x >> 6, lane = threadIdx.x & 63;
#pragma unroll
    for (int s = 0; s < 4; s++) {
        int R = wave * 32 + s * 8;               // 8-row group (8-aligned)
        int rl = R + (lane >> 3);
        int rg = row0 + rl;
        if (rg >= maxrow) rg = maxrow - 1;
        int chunk = (lane & 7) ^ (rl & 7);
        const _Float16* gp = gbase + (size_t)rg * rstride + kof + chunk * 8;
#if HAS_GLL
        gll16(gp, lds + R * 64);
#else
        *(half8*)&lds[rl * 64 + (lane & 7) * 8] = *(const half8*)gp;
#endif
    }
}

// fragment read honoring the swizzle: global chunk g (=ks*4+quad) of row r
__device__ __forceinline__ half8 frag(const _Float16* lds, int r, int g) {
    return *(const half8*)&lds[r * 64 + ((g ^ (r & 7)) * 8)];
}

// ---------------------------------------------------------------------------
// dtype detector: low u16 of each dword as bf16 exponent sanity test.
// ---------------------------------------------------------------------------
__global__ void detect_dtype(const unsigned short* __restrict__ states_u16,
                             int* __restrict__ flag) {
    __shared__ int cnt;
    if (threadIdx.x == 0) cnt = 0;
    __syncthreads();
    int local = 0;
    for (int i = threadIdx.x; i < 1024; i += 256) {
        unsigned short u = states_u16[2 * i];
        int e = (u >> 7) & 0xFF;
        if (e >= 96 && e <= 158) local++;
    }
    atomicAdd(&cnt, local);
    __syncthreads();
    if (threadIdx.x == 0) *flag = (cnt >= 512) ? 1 : 0;
}

__global__ void cast_h16(const void* __restrict__ in, _Float16* __restrict__ out,
                         const int* __restrict__ flag, int n) {
    int i = blockIdx.x * blockDim.x + threadIdx.x;
    if (i < n) out[i] = (_Float16)readf(in, i, *flag);
}

// type_W [L][t][k][c] -> BTw [L][c:128][t*128+k : 512]
__global__ void prep_BTw(const void* __restrict__ W, _Float16* __restrict__ BTw,
                         const int* __restrict__ flag, int total) {
    int i = blockIdx.x * 256 + threadIdx.x;
    if (i >= total) return;
    int l = i >> 16;            // 128*512 per layer
    int rem = i & 65535;
    int c = rem >> 9, kk = rem & 511;
    int t = kk >> 7, k = kk & 127;
    BTw[i] = (_Float16)readf(W, (((long)(l * NT + t) * H) + k) * H + c, *flag);
}

// gru kernels -> BTg2 [L][nc:512][k:256], gate-interleaved columns:
//   nc = g*64 + gate*16 + m, actual h-col c = g*16 + m, gate in {z,r,x,h}
__global__ void prep_BTg2(const void* __restrict__ gk, const void* __restrict__ gr,
                          _Float16* __restrict__ BTg, const int* __restrict__ flag,
                          int total) {
    int i = blockIdx.x * 256 + threadIdx.x;
    if (i >= total) return;
    int l = i >> 17;            // 512*256 per layer
    int rem = i & 131071;
    int nc = rem >> 8, k = rem & 255;
    int g = nc >> 6, gate = (nc >> 4) & 3, m = nc & 15;
    int c = g * 16 + m;
    int fl = *flag;
    float v = 0.0f;
    if (gate == 0) {
        v = (k < 128) ? readf(gk, ((long)l * H + k) * 384 + c, fl)
                      : readf(gr, ((long)l * H + (k - 128)) * 384 + c, fl);
    } else if (gate == 1) {
        v = (k < 128) ? readf(gk, ((long)l * H + k) * 384 + 128 + c, fl)
                      : readf(gr, ((long)l * H + (k - 128)) * 384 + 128 + c, fl);
    } else if (gate == 2) {
        if (k < 128) v = readf(gk, ((long)l * H + k) * 384 + 256 + c, fl);
    } else {
        if (k >= 128) v = readf(gr, ((long)l * H + (k - 128)) * 384 + 256 + c, fl);
    }
    BTg[i] = (_Float16)v;
}

// btab[L][t][128]=type_b; gbsum[L][256]=gb0+gb1 (z,r); gb0c/gb1c[L][128] (c-gate)
__global__ void prep_bias2(const void* __restrict__ type_b, const void* __restrict__ grub,
                           float* __restrict__ btab, float* __restrict__ gbsum,
                           float* __restrict__ gb0c, float* __restrict__ gb1c,
                           const int* __restrict__ flag, int LAYERS) {
    int i = blockIdx.x * 256 + threadIdx.x;
    int fl = *flag;
    if (i < LAYERS * NT * H) btab[i] = readf(type_b, i, fl);
    if (i < LAYERS * 256) {
        int l = i >> 8, c = i & 255;
        gbsum[i] = readf(grub, (long)l * 768 + c, fl) +
                   readf(grub, (long)l * 768 + 384 + c, fl);
    }
    if (i < LAYERS * H) {
        int l = i >> 7, c = i & 127;
        gb0c[i] = readf(grub, (long)l * 768 + 256 + c, fl);
        gb1c[i] = readf(grub, (long)l * 768 + 384 + 256 + c, fl);
    }
}

// ---------------------------------------------------------------------------
// bucket edges by (dst, type); counts4 pre-zeroed. counts4[NN][4] doubles as
// the int4 per-row count table for gemm_agg's bias epilogue (true counts).
// ---------------------------------------------------------------------------
__global__ void place_edges4(const int* __restrict__ edges, int* __restrict__ counts4,
                             int* __restrict__ buckets4, int NE) {
    int e = blockIdx.x * 256 + threadIdx.x;
    if (e >= NE) return;
    int t = edges[3 * e], src = edges[3 * e + 1], dst = edges[3 * e + 2];
    int slot = atomicAdd(&counts4[dst * 4 + t], 1);
    if (slot < CAP4) buckets4[((size_t)dst * 4 + t) * CAP4 + slot] = src;
}

// ---------------------------------------------------------------------------
// gather4 v2: one wave per node; quarter-wave q owns type-q's edge list.
// Lane i of group q reads h16[src][i*8 .. i*8+8) (16 lanes x 16B = one row).
// No type branching, no cross-lane reduction, one half8 store per group.
// ---------------------------------------------------------------------------
__global__ __launch_bounds__(256) void gather4(
    const _Float16* __restrict__ h16, const int* __restrict__ counts4,
    const int* __restrict__ buckets4, _Float16* __restrict__ A4, int NN) {
    int node = blockIdx.x * 4 + (threadIdx.x >> 6);
    int lane = threadIdx.x & 63;
    int q = lane >> 4, i = lane & 15;
    if (node >= NN) return;
    int cnt = counts4[node * 4 + q];
    if (cnt > CAP4) cnt = CAP4;
    const int* bkt = buckets4 + ((size_t)node * 4 + q) * CAP4;

    float acc[8] = {};
    int e = 0;
    for (; e + 2 <= cnt; e += 2) {
        int s0 = bkt[e], s1 = bkt[e + 1];
        half8 v0 = *(const half8*)&h16[(size_t)s0 * H + i * 8];
        half8 v1 = *(const half8*)&h16[(size_t)s1 * H + i * 8];
#pragma unroll
        for (int j = 0; j < 8; j++) acc[j] += (float)v0[j] + (float)v1[j];
    }
    if (e < cnt) {
        int s0 = bkt[e];
        half8 v0 = *(const half8*)&h16[(size_t)s0 * H + i * 8];
#pragma unroll
        for (int j = 0; j < 8; j++) acc[j] += (float)v0[j];
    }

    half8 o;
#pragma unroll
    for (int j = 0; j < 8; j++) o[j] = (_Float16)acc[j];
    *(half8*)&A4[((size_t)node * 4 + q) * H + i * 8] = o;
}

// ---------------------------------------------------------------------------
// agg GEMM: agg[row][c] = sum_k A4[row][k] * BTw[c][k] + cnt-weighted bias
// Block 128x128, K=512 (8 chunks of 64), 4 waves each 64x64.
// ---------------------------------------------------------------------------
__global__ __launch_bounds__(256) void gemm_agg(
    const _Float16* __restrict__ A4,    // [NN][512]
    const _Float16* __restrict__ BT,    // [128c][512k]
    _Float16* __restrict__ agg,         // [NN][128]
    const int4* __restrict__ cnt4, const float* __restrict__ btab,
    int Mrows) {
    __shared__ _Float16 As[128 * 64];
    __shared__ _Float16 Bs[128 * 64];

    const int row0 = blockIdx.x * 128;
    const int tid = threadIdx.x;
    const int wave = tid >> 6, lane = tid & 63;
    const int m = lane & 15, quad = lane >> 4;
    const int wr = (wave & 1) * 64, wc = (wave >> 1) * 64;

    f32x4 acc[4][4] = {};

    for (int kc = 0; kc < 8; kc++) {
        const int k0 = kc * BK;
        __syncthreads();
        stage_tile(A4, 512, row0, k0, Mrows, As);
        stage_tile(BT, 512, 0, k0, 128, Bs);
        __syncthreads();

#pragma unroll
        for (int ks = 0; ks < 2; ks++) {
            half8 a[4], b[4];
#pragma unroll
            for (int mt = 0; mt < 4; mt++)
                a[mt] = frag(As, wr + mt * 16 + m, ks * 4 + quad);
#pragma unroll
            for (int nt = 0; nt < 4; nt++)
                b[nt] = frag(Bs, wc + nt * 16 + m, ks * 4 + quad);
#pragma unroll
            for (int mt = 0; mt < 4; mt++)
#pragma unroll
                for (int nt = 0; nt < 4; nt++)
                    acc[mt][nt] = __builtin_amdgcn_mfma_f32_16x16x32_f16(
                        a[mt], b[nt], acc[mt][nt], 0, 0, 0);
        }
    }

#pragma unroll
    for (int mt = 0; mt < 4; mt++) {
#pragma unroll
        for (int i = 0; i < 4; i++) {
            int row = row0 + wr + mt * 16 + quad * 4 + i;
            if (row >= Mrows) continue;
            int4 c4 = cnt4[row];
#pragma unroll
            for (int nt = 0; nt < 4; nt++) {
                int cl = wc + nt * 16 + m;
                float bias = c4.x * btab[cl] + c4.y * btab[128 + cl] +
                             c4.z * btab[256 + cl] + c4.w * btab[384 + cl];
                agg[(size_t)row * H + cl] = (_Float16)(acc[mt][nt][i] + bias);
            }
        }
    }
}

// ---------------------------------------------------------------------------
// GRU GEMM with fused gate epilogue. 1-D grid with XCD-aware swizzle:
// all 4 y-partners of a row-tile share b%8 (same XCD) within a 32-block
// window, so A (agg+h) re-reads hit that XCD's L2.
// ---------------------------------------------------------------------------
__global__ __launch_bounds__(256) void gru_gemm_gate(
    const _Float16* __restrict__ agg16,  // [NN][128]
    const _Float16* __restrict__ h16,    // [NN][128]
    const _Float16* __restrict__ BT,     // [512nc][256k]
    const float* __restrict__ gbsum,     // [256]
    const float* __restrict__ gb0c,      // [128]
    const float* __restrict__ gb1c,      // [128]
    _Float16* __restrict__ hnext,        // [NN][128]
    void* __restrict__ outbuf,           // final output or nullptr
    const int* __restrict__ flag, int rtiles, int NN) {
    __shared__ _Float16 As[128 * 64];
    __shared__ _Float16 Bs[128 * 64];
    __shared__ _Float16 hg[128 * 32];    // h cols [32y, 32y+32) for gate blend

    // swizzle decode: b = macro*32 + y*8 + r_lo ; r = macro*8 + r_lo
    const int b = blockIdx.x;
    const int r_lo = b & 7, y = (b >> 3) & 3, macro = b >> 5;
    const int rt = macro * 8 + r_lo;
    if (rt >= rtiles) return;
    const int row0 = rt * 128;
    const int col0 = y * 128;
    const int tid = threadIdx.x;
    const int wave = tid >> 6, lane = tid & 63;
    const int m = lane & 15, quad = lane >> 4;
    const int wr = (wave & 1) * 64, wc = (wave >> 1) * 64;

    f32x4 acc[4][4] = {};

    for (int kc = 0; kc < 4; kc++) {
        const int k0 = kc * BK;
        __syncthreads();
        if (kc < 2) stage_tile(agg16, H, row0, k0, NN, As);
        else        stage_tile(h16, H, row0, k0 - 128, NN, As);
        stage_tile(BT, 256, col0, k0, 512, Bs);
        if (kc == 0) {
#pragma unroll
            for (int s = 0; s < 2; s++) {       // hg: 128 rows x 32 cols
                int idx = s * 256 + tid;        // 0..511 segments of 8 halfs
                int r = idx >> 2, cseg = (idx & 3) * 8;
                int rg = row0 + r;
                if (rg >= NN) rg = NN - 1;
                *(half8*)&hg[r * 32 + cseg] =
                    *(const half8*)&h16[(size_t)rg * H + y * 32 + cseg];
            }
        }
        __syncthreads();

#pragma unroll
        for (int ks = 0; ks < 2; ks++) {
            half8 a[4], b8[4];
#pragma unroll
            for (int mt = 0; mt < 4; mt++)
                a[mt] = frag(As, wr + mt * 16 + m, ks * 4 + quad);
#pragma unroll
            for (int nt = 0; nt < 4; nt++)
                b8[nt] = frag(Bs, wc + nt * 16 + m, ks * 4 + quad);
#pragma unroll
            for (int mt = 0; mt < 4; mt++)
#pragma unroll
                for (int nt = 0; nt < 4; nt++)
                    acc[mt][nt] = __builtin_amdgcn_mfma_f32_16x16x32_f16(
                        a[mt], b8[nt], acc[mt][nt], 0, 0, 0);
        }
    }

    // gate epilogue: this wave's col-group
    const int g = (col0 + wc) >> 6;      // 0..7
    const int c = g * 16 + m;            // h-column
    const int chg = (wc >> 2) + m;       // c - 32y
    const float bz = gbsum[c];
    const float br = gbsum[128 + c];
    const float bx = gb0c[c];
    const float bh = gb1c[c];
    const int fl = outbuf ? *flag : 0;

#pragma unroll
    for (int mt = 0; mt < 4; mt++) {
#pragma unroll
        for (int i = 0; i < 4; i++) {
            int rl = wr + mt * 16 + quad * 4 + i;
            int row = row0 + rl;
            if (row >= NN) continue;
            float z = fsigmoid(acc[mt][0][i] + bz);
            float r = fsigmoid(acc[mt][1][i] + br);
            float cc = ftanh((acc[mt][2][i] + bx) + r * (acc[mt][3][i] + bh));
            float hv = (float)hg[rl * 32 + chg];
            float hn = z * hv + (1.0f - z) * cc;
            size_t oi = (size_t)row * H + c;
            hnext[oi] = (_Float16)hn;
            if (outbuf) {
                if (fl) ((unsigned short*)outbuf)[oi] = f2bf(hn);
                else    ((float*)outbuf)[oi] = hn;
            }
        }
    }
}

// ---------------------------------------------------------------------------
extern "C" void kernel_launch(void* const* d_in, const int* in_sizes, int n_in,
                              void* d_out, int out_size, void* d_ws, size_t ws_size,
                              hipStream_t stream) {
    const void* states = d_in[0];
    const int*  edges  = (const int*)d_in[1];
    const void* type_W = d_in[2];
    const void* type_b = d_in[3];
    const void* gruk   = d_in[4];
    const void* grur   = d_in[5];
    const void* grub   = d_in[6];

    const int NN = in_sizes[0] / H;    // 50000
    const int NE = in_sizes[1] / 3;    // 400000
    const int nW = in_sizes[2];        // L*NT*128*128
    const int LAYERS = nW / (NT * H * H);

    // --- workspace layout ---
    char* w = (char*)d_ws;
    int* flag = (int*)w;                               w += 64;
    _Float16* h16A  = (_Float16*)w;                    w += (size_t)NN * H * 2;
    _Float16* h16B  = (_Float16*)w;                    w += (size_t)NN * H * 2;
    _Float16* agg16 = (_Float16*)w;                    w += (size_t)NN * H * 2;
    _Float16* A4    = (_Float16*)w;                    w += (size_t)NN * 4 * H * 2;
    _Float16* BTw = (_Float16*)w;                      w += (size_t)LAYERS * H * 512 * 2;
    _Float16* BTg = (_Float16*)w;                      w += (size_t)LAYERS * 512 * 256 * 2;
    float* btab  = (float*)w;                          w += (size_t)LAYERS * NT * H * 4;
    float* gbsum = (float*)w;                          w += (size_t)LAYERS * 256 * 4;
    float* gb0c  = (float*)w;                          w += (size_t)LAYERS * H * 4;
    float* gb1c  = (float*)w;                          w += (size_t)LAYERS * H * 4;
    int* counts4 = (int*)w;                            w += (size_t)NN * 4 * 4;
    int* buckets4 = (int*)w;                           // [NN][4][CAP4]

    detect_dtype<<<1, 256, 0, stream>>>((const unsigned short*)states, flag);

    cast_h16<<<(NN * H + 255) / 256, 256, 0, stream>>>(states, h16A, flag, NN * H);
    prep_BTw<<<(LAYERS * 65536 + 255) / 256, 256, 0, stream>>>(type_W, BTw, flag,
                                                               LAYERS * 65536);
    prep_BTg2<<<(LAYERS * 131072 + 255) / 256, 256, 0, stream>>>(gruk, grur, BTg, flag,
                                                                 LAYERS * 131072);
    prep_bias2<<<4, 256, 0, stream>>>(type_b, grub, btab, gbsum, gb0c, gb1c, flag, LAYERS);

    hipMemsetAsync(counts4, 0, (size_t)NN * 4 * 4, stream);
    place_edges4<<<(NE + 255) / 256, 256, 0, stream>>>(edges, counts4, buckets4, NE);

    const int rtiles = (NN + 127) / 128;
    const int nb_gru = ((rtiles + 7) / 8) * 32;
    for (int L = 0; L < LAYERS; L++) {
        const _Float16* hcur = (L & 1) ? h16B : h16A;
        _Float16* hnext      = (L & 1) ? h16A : h16B;

        gather4<<<(NN + 3) / 4, 256, 0, stream>>>(hcur, counts4, buckets4, A4, NN);

        gemm_agg<<<rtiles, 256, 0, stream>>>(
            A4, BTw + (size_t)L * H * 512, agg16,
            (const int4*)counts4, btab + (size_t)L * NT * H, NN);

        gru_gemm_gate<<<nb_gru, 256, 0, stream>>>(
            agg16, hcur,
            BTg + (size_t)L * 512 * 256,
            gbsum + (size_t)L * 256, gb0c + (size_t)L * H, gb1c + (size_t)L * H,
            hnext, (L == LAYERS - 1) ? d_out : nullptr, flag, rtiles, NN);
    }
}